// Round 1
// baseline (752.326 us; speedup 1.0000x reference)
//
#include <hip/hip_runtime.h>
#include <cstdint>
#include <cstddef>

#define NN 8192
#define EE 262144
#define ET 270336   // EE + NN self loops

using short8  = __attribute__((ext_vector_type(8))) short;
using floatx4 = __attribute__((ext_vector_type(4))) float;

__device__ __forceinline__ unsigned short f2bf(float f) {
  unsigned int u = __float_as_uint(f);
  u += 0x7fffu + ((u >> 16) & 1u);          // RNE
  return (unsigned short)(u >> 16);
}

// ---------------- CSR build (counting sort by dst) ----------------
__global__ void edge_hist_k(const int* __restrict__ ei, int* __restrict__ cnt) {
  int e = blockIdx.x * 256 + threadIdx.x;
  if (e >= ET) return;
  int d = (e < EE) ? ei[EE + e] : (e - EE);   // ei[1][e] is dst; tail = self loops
  atomicAdd(&cnt[d], 1);
}

__global__ void scan_k(int* cnt, int* off, int* pos) {   // cnt may alias pos
  __shared__ int s[1024];
  int t = threadIdx.x;
  int v[8]; int base = t * 8; int sum = 0;
  #pragma unroll
  for (int j = 0; j < 8; ++j) { v[j] = cnt[base + j]; sum += v[j]; }
  s[t] = sum; __syncthreads();
  for (int o = 1; o < 1024; o <<= 1) {
    int x = (t >= o) ? s[t - o] : 0;
    __syncthreads();
    s[t] += x;
    __syncthreads();
  }
  int excl = s[t] - sum;
  #pragma unroll
  for (int j = 0; j < 8; ++j) { off[base + j] = excl; pos[base + j] = excl; excl += v[j]; }
  if (t == 1023) off[NN] = excl;
}

__global__ void edge_scatter_k(const int* __restrict__ ei, int* __restrict__ pos,
                               int* __restrict__ srcs) {
  int e = blockIdx.x * 256 + threadIdx.x;
  if (e >= ET) return;
  int sv, d;
  if (e < EE) { sv = ei[e]; d = ei[EE + e]; } else { sv = d = e - EE; }
  int p = atomicAdd(&pos[d], 1);
  srcs[p] = sv;
}

// ---------------- generic small GEMM: C = act(A[M,K]@B[K,NC] + bias) ----------------
// grid=(M/64, NC/32), block=256, thread = 8 rows x 1 col. B strip cached in LDS.
__global__ __launch_bounds__(256) void gemm_k(const float* __restrict__ A, const float* __restrict__ B,
                                              const float* __restrict__ bias, float* __restrict__ Cf,
                                              unsigned short* __restrict__ Cb,
                                              int K, int NC, int lda, int ldc, int act) {
  __shared__ float Bs[256 * 32];
  const int tid = threadIdx.x;
  const int c0 = blockIdx.y * 32;
  const int row0 = blockIdx.x * 64 + (tid >> 5) * 8;
  const int col = tid & 31;
  for (int idx = tid; idx < K * 32; idx += 256)
    Bs[idx] = B[(idx >> 5) * NC + c0 + (idx & 31)];
  __syncthreads();
  float acc[8] = {0.f,0.f,0.f,0.f,0.f,0.f,0.f,0.f};
  for (int k = 0; k < K; k += 4) {
    float b0 = Bs[(k + 0) * 32 + col], b1 = Bs[(k + 1) * 32 + col];
    float b2 = Bs[(k + 2) * 32 + col], b3 = Bs[(k + 3) * 32 + col];
    #pragma unroll
    for (int r = 0; r < 8; ++r) {
      const float4 a4 = *(const float4*)(A + (size_t)(row0 + r) * lda + k);
      acc[r] = fmaf(a4.x, b0, acc[r]);
      acc[r] = fmaf(a4.y, b1, acc[r]);
      acc[r] = fmaf(a4.z, b2, acc[r]);
      acc[r] = fmaf(a4.w, b3, acc[r]);
    }
  }
  float bv = bias ? bias[c0 + col] : 0.f;
  #pragma unroll
  for (int r = 0; r < 8; ++r) {
    float o = acc[r] + bv;
    if (act == 1) o = fmaxf(o, 0.f);
    size_t oi = (size_t)(row0 + r) * ldc + c0 + col;
    if (Cb) Cb[oi] = f2bf(o); else Cf[oi] = o;
  }
}

// ---------------- per-(node,head) attention scalars a_s, a_d (C=64) ----------------
__global__ void att_sd_k(const float* __restrict__ h, const float* __restrict__ as_w,
                         const float* __restrict__ ad_w, float* __restrict__ a_s,
                         float* __restrict__ a_d, int H) {
  int idx = blockIdx.x * 256 + threadIdx.x;
  if (idx >= NN * H) return;
  int n = idx / H, hh = idx - n * H;
  const float4* hp = (const float4*)(h + ((size_t)n * H + hh) * 64);
  const float4* sp = (const float4*)(as_w + hh * 64);
  const float4* dp = (const float4*)(ad_w + hh * 64);
  float s = 0.f, d = 0.f;
  #pragma unroll
  for (int c = 0; c < 16; ++c) {
    float4 a = hp[c], b = sp[c], e = dp[c];
    s += a.x*b.x + a.y*b.y + a.z*b.z + a.w*b.w;
    d += a.x*e.x + a.y*e.y + a.z*e.z + a.w*e.w;
  }
  a_s[idx] = s; a_d[idx] = d;
}

// ---------------- GAT aggregation: one block per dst node, HC threads ----------------
// softmax without max-subtraction (mathematically identical); elu + bias fused.
template<int H, int C>
__global__ void gat_agg_k(const float* __restrict__ h, const float* __restrict__ a_s,
                          const float* __restrict__ a_d, const int* __restrict__ off,
                          const int* __restrict__ srcs, const float* __restrict__ bias,
                          float* __restrict__ out, int ldout) {
  constexpr int HC = H * C;
  const int b = blockIdx.x;
  const int tid = threadIdx.x;
  const int hd = tid / C;
  const int r0 = off[b], r1 = off[b + 1];
  __shared__ int s_src[HC];
  __shared__ float s_w[HC][H];
  float ad[H];
  #pragma unroll
  for (int hh = 0; hh < H; ++hh) ad[hh] = a_d[b * H + hh];
  float acc = 0.f, den = 0.f;
  for (int base = r0; base < r1; base += HC) {
    __syncthreads();
    int e = base + tid;
    if (e < r1) {
      int sv = srcs[e];
      s_src[tid] = sv;
      #pragma unroll
      for (int hh = 0; hh < H; ++hh) {
        float xv = a_s[sv * H + hh] + ad[hh];
        xv = xv > 0.f ? xv : 0.2f * xv;     // leaky_relu 0.2
        s_w[tid][hh] = __expf(xv);
      }
    }
    __syncthreads();
    int cnt = min(HC, r1 - base);
    for (int j = 0; j < cnt; ++j) {
      float wv = s_w[j][hd];
      den += wv;
      acc = fmaf(wv, h[(size_t)s_src[j] * HC + tid], acc);
    }
  }
  float o = acc / den + bias[tid];
  out[(size_t)b * ldout + tid] = o > 0.f ? o : (__expf(o) - 1.f);  // elu
}

// ---------------- GCN aggregation: one block (64 thr) per dst node ----------------
__global__ void gcn_agg_k(const float* __restrict__ hg, const int* __restrict__ off,
                          const int* __restrict__ srcs, const float* __restrict__ bias,
                          float* __restrict__ out, int ldout) {
  const int b = blockIdx.x, tid = threadIdx.x;
  int r0 = off[b], r1 = off[b + 1];
  float dinv_b = rsqrtf((float)max(r1 - r0, 1));
  __shared__ int s_src[64];
  __shared__ float s_nrm[64];
  float acc = 0.f;
  for (int base = r0; base < r1; base += 64) {
    __syncthreads();
    int e = base + tid;
    if (e < r1) {
      int sv = srcs[e];
      s_src[tid] = sv;
      int ds = off[sv + 1] - off[sv];
      s_nrm[tid] = dinv_b * rsqrtf((float)max(ds, 1));
    }
    __syncthreads();
    int cnt = min(64, r1 - base);
    for (int j = 0; j < cnt; ++j)
      acc = fmaf(s_nrm[j], hg[(size_t)s_src[j] * 64 + tid], acc);
  }
  float o = acc + bias[tid];
  out[(size_t)b * ldout + tid] = fmaxf(o, 0.f);
}

// ---------------- transpose V [N,64] f32 -> Vt [64,N] bf16 ----------------
__global__ void transpose_bf16_k(const float* __restrict__ v, unsigned short* __restrict__ Vt) {
  __shared__ float t[64][65];
  int b0 = blockIdx.x * 64;
  for (int idx = threadIdx.x; idx < 4096; idx += 256) {
    int r = idx >> 6, c = idx & 63;
    t[r][c] = v[(size_t)(b0 + r) * 64 + c];
  }
  __syncthreads();
  for (int idx = threadIdx.x; idx < 4096; idx += 256) {
    int c = idx >> 6, r = idx & 63;
    Vt[(size_t)c * NN + b0 + r] = f2bf(t[r][c]);
  }
}

// ---------------- attention pass 1: row sums l[q][h] = sum_k exp(s*SC) ----------------
// block = 256 (4 waves), 32 q-rows/block, wave owns 2048-key strip. One mfma = full d=32 dot.
__global__ __launch_bounds__(256) void att_pass1(const unsigned short* __restrict__ qb,
                                                 const unsigned short* __restrict__ kb,
                                                 float* __restrict__ lrow) {
  const int tid = threadIdx.x;
  const int lane = tid & 63, wv = tid >> 6;
  const int ql = lane & 15, quad = lane >> 4;
  const int qt0 = blockIdx.x * 32;
  const float SC = 0.17677669529663687f;  // 1/sqrt(32)
  const floatx4 zf = {0.f, 0.f, 0.f, 0.f};
  short8 qf[2][2];
  #pragma unroll
  for (int a = 0; a < 2; ++a)
    #pragma unroll
    for (int h = 0; h < 2; ++h)
      qf[a][h] = *(const short8*)(qb + (size_t)(qt0 + a*16 + ql) * 64 + h*32 + quad*8);
  float lacc[2][2][4];
  #pragma unroll
  for (int a = 0; a < 2; ++a)
    #pragma unroll
    for (int h = 0; h < 2; ++h)
      #pragma unroll
      for (int r = 0; r < 4; ++r) lacc[a][h][r] = 0.f;
  int kbase = wv * 2048;
  for (int it = 0; it < 64; ++it, kbase += 32) {
    short8 kf[2][2];
    #pragma unroll
    for (int kt = 0; kt < 2; ++kt)
      #pragma unroll
      for (int h = 0; h < 2; ++h)
        kf[kt][h] = *(const short8*)(kb + (size_t)(kbase + kt*16 + ql) * 64 + h*32 + quad*8);
    #pragma unroll
    for (int a = 0; a < 2; ++a)
      #pragma unroll
      for (int h = 0; h < 2; ++h)
        #pragma unroll
        for (int kt = 0; kt < 2; ++kt) {
          floatx4 s = __builtin_amdgcn_mfma_f32_16x16x32_bf16(qf[a][h], kf[kt][h], zf, 0, 0, 0);
          #pragma unroll
          for (int r = 0; r < 4; ++r) lacc[a][h][r] += __expf(s[r] * SC);
        }
  }
  #pragma unroll
  for (int o = 8; o >= 1; o >>= 1)
    #pragma unroll
    for (int a = 0; a < 2; ++a)
      #pragma unroll
      for (int h = 0; h < 2; ++h)
        #pragma unroll
        for (int r = 0; r < 4; ++r)
          lacc[a][h][r] += __shfl_xor(lacc[a][h][r], o, 16);
  if (ql == 0) {
    #pragma unroll
    for (int a = 0; a < 2; ++a)
      #pragma unroll
      for (int h = 0; h < 2; ++h)
        #pragma unroll
        for (int r = 0; r < 4; ++r)
          atomicAdd(&lrow[(size_t)(qt0 + a*16 + quad*4 + r) * 2 + h], lacc[a][h][r]);
  }
}

// ---------------- attention pass 2: write p_mean to d_out, accumulate O = P@V ----------------
__global__ __launch_bounds__(256) void att_pass2(
    const unsigned short* __restrict__ qb, const unsigned short* __restrict__ kb,
    const unsigned short* __restrict__ Vt, const float* __restrict__ lrow,
    float* __restrict__ attn, float* __restrict__ O) {
  __shared__ __align__(16) float Esh[4][2][16 * 36];  // [wave][head][16q x 32k, stride 36]
  __shared__ float Osh[32 * 64];
  const int tid = threadIdx.x;
  const int lane = tid & 63, wv = tid >> 6;
  const int ql = lane & 15, quad = lane >> 4;
  const int qt0 = blockIdx.x * 32;
  const float SC = 0.17677669529663687f;
  const floatx4 zf = {0.f, 0.f, 0.f, 0.f};

  for (int idx = tid; idx < 32 * 64; idx += 256) Osh[idx] = 0.f;
  __syncthreads();

  short8 qf[2][2];
  #pragma unroll
  for (int a = 0; a < 2; ++a)
    #pragma unroll
    for (int h = 0; h < 2; ++h)
      qf[a][h] = *(const short8*)(qb + (size_t)(qt0 + a*16 + ql) * 64 + h*32 + quad*8);

  float invl[2][2][4];
  #pragma unroll
  for (int a = 0; a < 2; ++a)
    #pragma unroll
    for (int h = 0; h < 2; ++h)
      #pragma unroll
      for (int r = 0; r < 4; ++r)
        invl[a][h][r] = 1.0f / lrow[(size_t)(qt0 + a*16 + quad*4 + r) * 2 + h];

  floatx4 oacc[2][2][2];
  #pragma unroll
  for (int a = 0; a < 2; ++a)
    #pragma unroll
    for (int h = 0; h < 2; ++h)
      #pragma unroll
      for (int hf = 0; hf < 2; ++hf) oacc[a][h][hf] = zf;

  int kbase = wv * 2048;
  for (int it = 0; it < 64; ++it, kbase += 32) {
    short8 kf[2][2], vf[2][2];
    #pragma unroll
    for (int kt = 0; kt < 2; ++kt)
      #pragma unroll
      for (int h = 0; h < 2; ++h)
        kf[kt][h] = *(const short8*)(kb + (size_t)(kbase + kt*16 + ql) * 64 + h*32 + quad*8);
    #pragma unroll
    for (int h = 0; h < 2; ++h)
      #pragma unroll
      for (int hf = 0; hf < 2; ++hf)
        vf[h][hf] = *(const short8*)(Vt + (size_t)(h*32 + hf*16 + ql) * NN + kbase + quad*8);

    #pragma unroll
    for (int a = 0; a < 2; ++a) {
      floatx4 p[2][2];  // [head][kt]
      #pragma unroll
      for (int h = 0; h < 2; ++h)
        #pragma unroll
        for (int kt = 0; kt < 2; ++kt) {
          floatx4 s = __builtin_amdgcn_mfma_f32_16x16x32_bf16(qf[a][h], kf[kt][h], zf, 0, 0, 0);
          #pragma unroll
          for (int r = 0; r < 4; ++r)
            p[h][kt][r] = __expf(s[r] * SC) * invl[a][h][r];
        }
      // head-mean attention weights -> output (64B contiguous per quad)
      #pragma unroll
      for (int kt = 0; kt < 2; ++kt)
        #pragma unroll
        for (int r = 0; r < 4; ++r) {
          size_t row = (size_t)(qt0 + a*16 + quad*4 + r);
          attn[row * NN + kbase + kt*16 + ql] = 0.5f * (p[0][kt][r] + p[1][kt][r]);
        }
      // C-layout -> LDS -> A-layout round trip, then PV mfma
      #pragma unroll
      for (int h = 0; h < 2; ++h)
        #pragma unroll
        for (int kt = 0; kt < 2; ++kt)
          #pragma unroll
          for (int r = 0; r < 4; ++r)
            Esh[wv][h][(quad*4 + r) * 36 + kt*16 + ql] = p[h][kt][r];
      #pragma unroll
      for (int h = 0; h < 2; ++h) {
        const float* ep = &Esh[wv][h][ql * 36 + quad * 8];
        float4 x0 = *(const float4*)ep;
        float4 x1 = *(const float4*)(ep + 4);
        short8 ef;
        ef[0] = (short)f2bf(x0.x); ef[1] = (short)f2bf(x0.y);
        ef[2] = (short)f2bf(x0.z); ef[3] = (short)f2bf(x0.w);
        ef[4] = (short)f2bf(x1.x); ef[5] = (short)f2bf(x1.y);
        ef[6] = (short)f2bf(x1.z); ef[7] = (short)f2bf(x1.w);
        #pragma unroll
        for (int hf = 0; hf < 2; ++hf)
          oacc[a][h][hf] = __builtin_amdgcn_mfma_f32_16x16x32_bf16(ef, vf[h][hf], oacc[a][h][hf], 0, 0, 0);
      }
    }
  }
  #pragma unroll
  for (int a = 0; a < 2; ++a)
    #pragma unroll
    for (int h = 0; h < 2; ++h)
      #pragma unroll
      for (int hf = 0; hf < 2; ++hf)
        #pragma unroll
        for (int r = 0; r < 4; ++r)
          atomicAdd(&Osh[(a*16 + quad*4 + r) * 64 + h*32 + hf*16 + ql], oacc[a][h][hf][r]);
  __syncthreads();
  for (int idx = tid; idx < 32 * 64; idx += 256)
    O[(size_t)qt0 * 64 + idx] = Osh[idx];
}

// ---------------- final prediction head: pred = y1 @ fc2_W + fc2_b ----------------
__global__ void pred_k(const float* __restrict__ y1, const float* __restrict__ W2,
                       const float* __restrict__ b2, float* __restrict__ out) {
  int i = blockIdx.x * 256 + threadIdx.x;
  const float4* yp = (const float4*)(y1 + (size_t)i * 64);
  float s = b2[0];
  #pragma unroll
  for (int c4 = 0; c4 < 16; ++c4) {
    float4 a = yp[c4];
    float4 wv = *(const float4*)(W2 + c4 * 4);
    s += a.x*wv.x + a.y*wv.y + a.z*wv.z + a.w*wv.w;
  }
  out[i] = s;
}

extern "C" void kernel_launch(void* const* d_in, const int* in_sizes, int n_in,
                              void* d_out, int out_size, void* d_ws, size_t ws_size,
                              hipStream_t stream) {
  (void)in_sizes; (void)n_in; (void)out_size; (void)ws_size;
  const float* x       = (const float*)d_in[0];
  const int*   ei_t    = (const int*)d_in[1];
  const int*   ei_e    = (const int*)d_in[2];
  const float* gat1_W  = (const float*)d_in[3];
  const float* gat1_as = (const float*)d_in[4];
  const float* gat1_ad = (const float*)d_in[5];
  const float* gat1_b  = (const float*)d_in[6];
  const float* gat2_W  = (const float*)d_in[7];
  const float* gat2_as = (const float*)d_in[8];
  const float* gat2_ad = (const float*)d_in[9];
  const float* gat2_b  = (const float*)d_in[10];
  const float* gcn1_W  = (const float*)d_in[11];
  const float* gcn1_b  = (const float*)d_in[12];
  const float* gcn2_W  = (const float*)d_in[13];
  const float* gcn2_b  = (const float*)d_in[14];
  const float* Wq = (const float*)d_in[15]; const float* bq = (const float*)d_in[16];
  const float* Wk = (const float*)d_in[17]; const float* bk = (const float*)d_in[18];
  const float* Wv = (const float*)d_in[19]; const float* bv = (const float*)d_in[20];
  const float* Wo = (const float*)d_in[21]; const float* bo = (const float*)d_in[22];
  const float* fc1_W = (const float*)d_in[23]; const float* fc1_b = (const float*)d_in[24];
  const float* fc2_W = (const float*)d_in[25]; const float* fc2_b = (const float*)d_in[26];

  float* out  = (float*)d_out;
  float* attn = out + NN;   // [N, N] fp32, after pred[N]

  char* wsp = (char*)d_ws;
  size_t ofs = 0;
  auto take = [&](size_t bytes) -> char* {
    char* p = wsp + ofs;
    ofs = (ofs + bytes + 255) & ~(size_t)255;
    return p;
  };
  int* off_t = (int*)take((NN + 1) * 4);
  int* pos_t = (int*)take(NN * 4);
  int* src_t = (int*)take((size_t)ET * 4);
  int* off_e = (int*)take((NN + 1) * 4);
  int* pos_e = (int*)take(NN * 4);
  int* src_e = (int*)take((size_t)ET * 4);
  float* h1     = (float*)take((size_t)NN * 128 * 4);
  float* g1out  = (float*)take((size_t)NN * 128 * 4);
  float* a_s1   = (float*)take((size_t)NN * 2 * 4);
  float* a_d1   = (float*)take((size_t)NN * 2 * 4);
  float* h2     = (float*)take((size_t)NN * 64 * 4);
  float* a_s2   = (float*)take((size_t)NN * 4);
  float* a_d2   = (float*)take((size_t)NN * 4);
  float* hg1    = (float*)take((size_t)NN * 64 * 4);
  float* g1c    = (float*)take((size_t)NN * 64 * 4);
  float* hg2    = (float*)take((size_t)NN * 64 * 4);
  float* hekg   = (float*)take((size_t)NN * 64 * 4);
  float* hfused = (float*)take((size_t)NN * 128 * 4);
  unsigned short* qb = (unsigned short*)take((size_t)NN * 64 * 2);
  unsigned short* kb = (unsigned short*)take((size_t)NN * 64 * 2);
  float* vtmp   = (float*)take((size_t)NN * 64 * 4);
  unsigned short* Vt = (unsigned short*)take((size_t)64 * NN * 2);
  float* lbuf   = (float*)take((size_t)NN * 2 * 4);
  float* Obuf   = (float*)take((size_t)NN * 64 * 4);
  float* y1     = (float*)take((size_t)NN * 64 * 4);

  hipMemsetAsync(pos_t, 0, NN * 4, stream);
  hipMemsetAsync(pos_e, 0, NN * 4, stream);
  hipMemsetAsync(lbuf, 0, NN * 2 * 4, stream);

  // CSR by dst for both graphs
  edge_hist_k<<<ET / 256, 256, 0, stream>>>(ei_t, pos_t);
  scan_k<<<1, 1024, 0, stream>>>(pos_t, off_t, pos_t);
  edge_scatter_k<<<ET / 256, 256, 0, stream>>>(ei_t, pos_t, src_t);
  edge_hist_k<<<ET / 256, 256, 0, stream>>>(ei_e, pos_e);
  scan_k<<<1, 1024, 0, stream>>>(pos_e, off_e, pos_e);
  edge_scatter_k<<<ET / 256, 256, 0, stream>>>(ei_e, pos_e, src_e);

  // GAT branch
  gemm_k<<<dim3(128, 4), 256, 0, stream>>>(x, gat1_W, nullptr, h1, nullptr, 256, 128, 256, 128, 0);
  att_sd_k<<<(NN * 2) / 256, 256, 0, stream>>>(h1, gat1_as, gat1_ad, a_s1, a_d1, 2);
  gat_agg_k<2, 64><<<NN, 128, 0, stream>>>(h1, a_s1, a_d1, off_t, src_t, gat1_b, g1out, 128);
  gemm_k<<<dim3(128, 2), 256, 0, stream>>>(g1out, gat2_W, nullptr, h2, nullptr, 128, 64, 128, 64, 0);
  att_sd_k<<<NN / 256, 256, 0, stream>>>(h2, gat2_as, gat2_ad, a_s2, a_d2, 1);
  gat_agg_k<1, 64><<<NN, 64, 0, stream>>>(h2, a_s2, a_d2, off_t, src_t, gat2_b, hfused, 128);

  // GCN branch
  gemm_k<<<dim3(128, 2), 256, 0, stream>>>(x, gcn1_W, nullptr, hg1, nullptr, 256, 64, 256, 64, 0);
  gcn_agg_k<<<NN, 64, 0, stream>>>(hg1, off_e, src_e, gcn1_b, g1c, 64);
  gemm_k<<<dim3(128, 2), 256, 0, stream>>>(g1c, gcn2_W, nullptr, hg2, nullptr, 64, 64, 64, 64, 0);
  gcn_agg_k<<<NN, 64, 0, stream>>>(hg2, off_e, src_e, gcn2_b, hekg, 64);

  // q, k, v projections (bf16 for MFMA); Vt = V^T bf16
  gemm_k<<<dim3(128, 2), 256, 0, stream>>>(hfused, Wq, bq, nullptr, qb, 64, 64, 128, 64, 0);
  gemm_k<<<dim3(128, 2), 256, 0, stream>>>(hekg, Wk, bk, nullptr, kb, 64, 64, 64, 64, 0);
  gemm_k<<<dim3(128, 2), 256, 0, stream>>>(hekg, Wv, bv, vtmp, nullptr, 64, 64, 64, 64, 0);
  transpose_bf16_k<<<128, 256, 0, stream>>>(vtmp, Vt);

  // attention
  att_pass1<<<256, 256, 0, stream>>>(qb, kb, lbuf);
  att_pass2<<<256, 256, 0, stream>>>(qb, kb, Vt, lbuf, attn, Obuf);

  // epilogue: h_attn = O@Wo+bo into hfused[:,64:], then MLP head
  gemm_k<<<dim3(128, 2), 256, 0, stream>>>(Obuf, Wo, bo, hfused + 64, nullptr, 64, 64, 64, 128, 0);
  gemm_k<<<dim3(128, 2), 256, 0, stream>>>(hfused, fc1_W, fc1_b, y1, nullptr, 128, 64, 128, 64, 1);
  pred_k<<<NN / 256, 256, 0, stream>>>(y1, fc2_W, fc2_b, out);
}

// Round 2
// 668.878 us; speedup vs baseline: 1.1248x; 1.1248x over previous
//
#include <hip/hip_runtime.h>
#include <cstdint>
#include <cstddef>

#define NN 8192
#define EE 262144
#define ET 270336   // EE + NN self loops

using short8  = __attribute__((ext_vector_type(8))) short;
using floatx4 = __attribute__((ext_vector_type(4))) float;

__device__ __forceinline__ unsigned short f2bf(float f) {
  unsigned int u = __float_as_uint(f);
  u += 0x7fffu + ((u >> 16) & 1u);          // RNE
  return (unsigned short)(u >> 16);
}

// ---------------- CSR build, both graphs in one launch ----------------
__global__ void edge_hist2_k(const int* __restrict__ ei_t, const int* __restrict__ ei_e,
                             int* __restrict__ cnt_t, int* __restrict__ cnt_e) {
  int idx = blockIdx.x * 256 + threadIdx.x;
  int g = idx >= ET;                        // block-uniform (ET % 256 == 0)
  int e = g ? idx - ET : idx;
  const int* ei = g ? ei_e : ei_t;
  int* cnt = g ? cnt_e : cnt_t;
  int d = (e < EE) ? ei[EE + e] : (e - EE);
  atomicAdd(&cnt[d], 1);
}

__global__ void scan2_k(int* cnt_t, int* off_t, int* cnt_e, int* off_e) {
  int* cnt = blockIdx.x ? cnt_e : cnt_t;    // pos aliases cnt (overwritten)
  int* off = blockIdx.x ? off_e : off_t;
  __shared__ int s[1024];
  int t = threadIdx.x;
  int v[8]; int base = t * 8; int sum = 0;
  #pragma unroll
  for (int j = 0; j < 8; ++j) { v[j] = cnt[base + j]; sum += v[j]; }
  s[t] = sum; __syncthreads();
  for (int o = 1; o < 1024; o <<= 1) {
    int x = (t >= o) ? s[t - o] : 0;
    __syncthreads();
    s[t] += x;
    __syncthreads();
  }
  int excl = s[t] - sum;
  #pragma unroll
  for (int j = 0; j < 8; ++j) { off[base + j] = excl; cnt[base + j] = excl; excl += v[j]; }
  if (t == 1023) off[NN] = excl;
}

__global__ void edge_scatter2_k(const int* __restrict__ ei_t, const int* __restrict__ ei_e,
                                int* __restrict__ pos_t, int* __restrict__ pos_e,
                                int* __restrict__ srcs_t, int* __restrict__ srcs_e) {
  int idx = blockIdx.x * 256 + threadIdx.x;
  int g = idx >= ET;
  int e = g ? idx - ET : idx;
  const int* ei = g ? ei_e : ei_t;
  int* pos = g ? pos_e : pos_t;
  int* srcs = g ? srcs_e : srcs_t;
  int sv, d;
  if (e < EE) { sv = ei[e]; d = ei[EE + e]; } else { sv = d = e - EE; }
  int p = atomicAdd(&pos[d], 1);
  srcs[p] = sv;
}

// ---------------- shared GEMM inner loop ----------------
__device__ __forceinline__ void gemm_core(const float* __restrict__ A, int lda, int K,
                                          const float* __restrict__ Bs, int row0, int col,
                                          float acc[8]) {
  #pragma unroll
  for (int r = 0; r < 8; ++r) acc[r] = 0.f;
  for (int k = 0; k < K; k += 4) {
    float b0 = Bs[(k + 0) * 32 + col], b1 = Bs[(k + 1) * 32 + col];
    float b2 = Bs[(k + 2) * 32 + col], b3 = Bs[(k + 3) * 32 + col];
    #pragma unroll
    for (int r = 0; r < 8; ++r) {
      const float4 a4 = *(const float4*)(A + (size_t)(row0 + r) * lda + k);
      acc[r] = fmaf(a4.x, b0, acc[r]);
      acc[r] = fmaf(a4.y, b1, acc[r]);
      acc[r] = fmaf(a4.z, b2, acc[r]);
      acc[r] = fmaf(a4.w, b3, acc[r]);
    }
  }
}

// ---------------- mm_x: h1 = x@gat1_W (+att_sd epilogue), hg1 = x@gcn1_W ----------------
// grid (128, 6): by 0..3 -> gat cols, by 4..5 -> gcn cols
__global__ __launch_bounds__(256) void mm_x_k(const float* __restrict__ x,
    const float* __restrict__ Wgat, const float* __restrict__ Wgcn,
    const float* __restrict__ as_w, const float* __restrict__ ad_w,
    float* __restrict__ h1, float* __restrict__ hg1,
    float* __restrict__ a_s1, float* __restrict__ a_d1) {
  __shared__ float Bs[256 * 32];
  const int tid = threadIdx.x, by = blockIdx.y;
  const bool gat = by < 4;
  const int NC = gat ? 128 : 64;
  const int c0 = gat ? by * 32 : (by - 4) * 32;
  const float* B = gat ? Wgat : Wgcn;
  for (int idx = tid; idx < 256 * 32; idx += 256)
    Bs[idx] = B[(idx >> 5) * NC + c0 + (idx & 31)];
  __syncthreads();
  const int row0 = blockIdx.x * 64 + (tid >> 5) * 8;
  const int col = tid & 31;
  float acc[8];
  gemm_core(x, 256, 256, Bs, row0, col, acc);
  if (gat) {
    #pragma unroll
    for (int r = 0; r < 8; ++r) h1[(size_t)(row0 + r) * 128 + c0 + col] = acc[r];
    const int head = c0 >> 6;
    const float asw = as_w[head * 64 + (c0 & 63) + col];
    const float adw = ad_w[head * 64 + (c0 & 63) + col];
    float ps[8], pd[8];
    #pragma unroll
    for (int r = 0; r < 8; ++r) { ps[r] = acc[r] * asw; pd[r] = acc[r] * adw; }
    #pragma unroll
    for (int m = 16; m >= 1; m >>= 1)
      #pragma unroll
      for (int r = 0; r < 8; ++r) { ps[r] += __shfl_xor(ps[r], m); pd[r] += __shfl_xor(pd[r], m); }
    if (col == 0) {
      #pragma unroll
      for (int r = 0; r < 8; ++r) {
        atomicAdd(&a_s1[(row0 + r) * 2 + head], ps[r]);
        atomicAdd(&a_d1[(row0 + r) * 2 + head], pd[r]);
      }
    }
  } else {
    #pragma unroll
    for (int r = 0; r < 8; ++r) hg1[(size_t)(row0 + r) * 64 + c0 + col] = acc[r];
  }
}

// ---------------- mm_gat2: h2 = g1out@gat2_W (+att_sd2 epilogue) ----------------
__global__ __launch_bounds__(256) void mm_gat2_k(const float* __restrict__ A,
    const float* __restrict__ W, const float* __restrict__ as_w, const float* __restrict__ ad_w,
    float* __restrict__ h2, float* __restrict__ a_s2, float* __restrict__ a_d2) {
  __shared__ float Bs[128 * 32];
  const int tid = threadIdx.x;
  const int c0 = blockIdx.y * 32;
  for (int idx = tid; idx < 128 * 32; idx += 256)
    Bs[idx] = W[(idx >> 5) * 64 + c0 + (idx & 31)];
  __syncthreads();
  const int row0 = blockIdx.x * 64 + (tid >> 5) * 8;
  const int col = tid & 31;
  float acc[8];
  gemm_core(A, 128, 128, Bs, row0, col, acc);
  const float asw = as_w[c0 + col];
  const float adw = ad_w[c0 + col];
  float ps[8], pd[8];
  #pragma unroll
  for (int r = 0; r < 8; ++r) {
    h2[(size_t)(row0 + r) * 64 + c0 + col] = acc[r];
    ps[r] = acc[r] * asw; pd[r] = acc[r] * adw;
  }
  #pragma unroll
  for (int m = 16; m >= 1; m >>= 1)
    #pragma unroll
    for (int r = 0; r < 8; ++r) { ps[r] += __shfl_xor(ps[r], m); pd[r] += __shfl_xor(pd[r], m); }
  if (col == 0) {
    #pragma unroll
    for (int r = 0; r < 8; ++r) {
      atomicAdd(&a_s2[row0 + r], ps[r]);
      atomicAdd(&a_d2[row0 + r], pd[r]);
    }
  }
}

// ---------------- GAT aggregation ----------------
template<int H, int C>
__global__ void gat_agg_k(const float* __restrict__ h, const float* __restrict__ a_s,
                          const float* __restrict__ a_d, const int* __restrict__ off,
                          const int* __restrict__ srcs, const float* __restrict__ bias,
                          float* __restrict__ out, int ldout) {
  constexpr int HC = H * C;
  const int b = blockIdx.x;
  const int tid = threadIdx.x;
  const int hd = tid / C;
  const int r0 = off[b], r1 = off[b + 1];
  __shared__ int s_src[HC];
  __shared__ float s_w[HC][H];
  float ad[H];
  #pragma unroll
  for (int hh = 0; hh < H; ++hh) ad[hh] = a_d[b * H + hh];
  float acc = 0.f, den = 0.f;
  for (int base = r0; base < r1; base += HC) {
    __syncthreads();
    int e = base + tid;
    if (e < r1) {
      int sv = srcs[e];
      s_src[tid] = sv;
      #pragma unroll
      for (int hh = 0; hh < H; ++hh) {
        float xv = a_s[sv * H + hh] + ad[hh];
        xv = xv > 0.f ? xv : 0.2f * xv;     // leaky_relu 0.2
        s_w[tid][hh] = __expf(xv);
      }
    }
    __syncthreads();
    int cnt = min(HC, r1 - base);
    for (int j = 0; j < cnt; ++j) {
      float wv = s_w[j][hd];
      den += wv;
      acc = fmaf(wv, h[(size_t)s_src[j] * HC + tid], acc);
    }
  }
  float o = acc / den + bias[tid];
  out[(size_t)b * ldout + tid] = o > 0.f ? o : (__expf(o) - 1.f);  // elu
}

// ---------------- GCN agg layer1 + fused gcn2 GEMV: h2g = relu(agg+b1)@W2 ----------------
__global__ void gcn_agg1_k(const float* __restrict__ hg1, const int* __restrict__ off,
                           const int* __restrict__ srcs, const float* __restrict__ b1,
                           const float* __restrict__ W2, float* __restrict__ h2g) {
  const int b = blockIdx.x, tid = threadIdx.x;
  int r0 = off[b], r1 = off[b + 1];
  float dinv_b = rsqrtf((float)max(r1 - r0, 1));
  __shared__ int s_src[64];
  __shared__ float s_nrm[64];
  __shared__ float s_row[64];
  float acc = 0.f;
  for (int base = r0; base < r1; base += 64) {
    __syncthreads();
    int e = base + tid;
    if (e < r1) {
      int sv = srcs[e];
      s_src[tid] = sv;
      int ds = off[sv + 1] - off[sv];
      s_nrm[tid] = dinv_b * rsqrtf((float)max(ds, 1));
    }
    __syncthreads();
    int cnt = min(64, r1 - base);
    for (int j = 0; j < cnt; ++j)
      acc = fmaf(s_nrm[j], hg1[(size_t)s_src[j] * 64 + tid], acc);
  }
  s_row[tid] = fmaxf(acc + b1[tid], 0.f);
  __syncthreads();
  float acc2 = 0.f;
  for (int k = 0; k < 64; ++k)
    acc2 = fmaf(s_row[k], W2[k * 64 + tid], acc2);
  h2g[(size_t)b * 64 + tid] = acc2;
}

// ---------------- GCN agg layer2: hekg = relu(agg(h2g)+b2) ----------------
__global__ void gcn_agg2_k(const float* __restrict__ h2g, const int* __restrict__ off,
                           const int* __restrict__ srcs, const float* __restrict__ bias,
                           float* __restrict__ out) {
  const int b = blockIdx.x, tid = threadIdx.x;
  int r0 = off[b], r1 = off[b + 1];
  float dinv_b = rsqrtf((float)max(r1 - r0, 1));
  __shared__ int s_src[64];
  __shared__ float s_nrm[64];
  float acc = 0.f;
  for (int base = r0; base < r1; base += 64) {
    __syncthreads();
    int e = base + tid;
    if (e < r1) {
      int sv = srcs[e];
      s_src[tid] = sv;
      int ds = off[sv + 1] - off[sv];
      s_nrm[tid] = dinv_b * rsqrtf((float)max(ds, 1));
    }
    __syncthreads();
    int cnt = min(64, r1 - base);
    for (int j = 0; j < cnt; ++j)
      acc = fmaf(s_nrm[j], h2g[(size_t)s_src[j] * 64 + tid], acc);
  }
  out[(size_t)b * 64 + tid] = fmaxf(acc + bias[tid], 0.f);
}

// ---------------- qkv projections (+V transpose) ----------------
// grid (128, 6): by>>1 = 0:q 1:k 2:v ; q pre-scaled by (1/sqrt(32))*log2(e)
__global__ __launch_bounds__(256) void mm_qkv_k(const float* __restrict__ htkg,
    const float* __restrict__ hekg,
    const float* __restrict__ Wq, const float* __restrict__ bq,
    const float* __restrict__ Wk, const float* __restrict__ bk,
    const float* __restrict__ Wv, const float* __restrict__ bv,
    unsigned short* __restrict__ qb, unsigned short* __restrict__ kb,
    unsigned short* __restrict__ Vt) {
  __shared__ float Bs[64 * 32];
  __shared__ float Ts[32][65];
  const int tid = threadIdx.x, by = blockIdx.y;
  const int kind = by >> 1;
  const int c0 = (by & 1) * 32;
  const float* A = (kind == 0) ? htkg : hekg;
  const float* B = (kind == 0) ? Wq : (kind == 1) ? Wk : Wv;
  const float* bias = (kind == 0) ? bq : (kind == 1) ? bk : bv;
  for (int idx = tid; idx < 64 * 32; idx += 256)
    Bs[idx] = B[(idx >> 5) * 64 + c0 + (idx & 31)];
  __syncthreads();
  const int row0 = blockIdx.x * 64 + (tid >> 5) * 8;
  const int col = tid & 31;
  float acc[8];
  gemm_core(A, 64, 64, Bs, row0, col, acc);
  const float bb = bias[c0 + col];
  if (kind == 0) {
    const float SCL = 0.17677669529663687f * 1.4426950408889634f;
    #pragma unroll
    for (int r = 0; r < 8; ++r)
      qb[(size_t)(row0 + r) * 64 + c0 + col] = f2bf((acc[r] + bb) * SCL);
  } else if (kind == 1) {
    #pragma unroll
    for (int r = 0; r < 8; ++r)
      kb[(size_t)(row0 + r) * 64 + c0 + col] = f2bf(acc[r] + bb);
  } else {
    const int rl = (tid >> 5) * 8;
    #pragma unroll
    for (int r = 0; r < 8; ++r) Ts[col][rl + r] = acc[r] + bb;
    __syncthreads();
    const int c = tid >> 3, rr = (tid & 7) * 8;
    short8 pk;
    #pragma unroll
    for (int j = 0; j < 8; ++j) pk[j] = (short)f2bf(Ts[c][rr + j]);
    *(short8*)(Vt + (size_t)(c0 + c) * NN + blockIdx.x * 64 + rr) = pk;
  }
}

// ---------------- attention pass 1: lrow[q][h] = sum_k exp2(s) ----------------
// grid 512 x 16 q-rows; wave strip = 2048 keys
__global__ __launch_bounds__(256) void att_pass1(const unsigned short* __restrict__ qb,
                                                 const unsigned short* __restrict__ kb,
                                                 float* __restrict__ lrow) {
  const int tid = threadIdx.x;
  const int lane = tid & 63, wv = tid >> 6;
  const int ql = lane & 15, quad = lane >> 4;
  const int qt0 = blockIdx.x * 16;
  const floatx4 zf = {0.f, 0.f, 0.f, 0.f};
  short8 qf[2];
  #pragma unroll
  for (int h = 0; h < 2; ++h)
    qf[h] = *(const short8*)(qb + (size_t)(qt0 + ql) * 64 + h * 32 + quad * 8);
  float lacc[2][4];
  #pragma unroll
  for (int h = 0; h < 2; ++h)
    #pragma unroll
    for (int r = 0; r < 4; ++r) lacc[h][r] = 0.f;
  int kbase = wv * 2048;
  for (int it = 0; it < 64; ++it, kbase += 32) {
    short8 kf[2][2];
    #pragma unroll
    for (int kt = 0; kt < 2; ++kt)
      #pragma unroll
      for (int h = 0; h < 2; ++h)
        kf[kt][h] = *(const short8*)(kb + (size_t)(kbase + kt * 16 + ql) * 64 + h * 32 + quad * 8);
    #pragma unroll
    for (int h = 0; h < 2; ++h)
      #pragma unroll
      for (int kt = 0; kt < 2; ++kt) {
        floatx4 s = __builtin_amdgcn_mfma_f32_16x16x32_bf16(qf[h], kf[kt][h], zf, 0, 0, 0);
        #pragma unroll
        for (int r = 0; r < 4; ++r) lacc[h][r] += __builtin_amdgcn_exp2f(s[r]);
      }
  }
  #pragma unroll
  for (int o = 8; o >= 1; o >>= 1)
    #pragma unroll
    for (int h = 0; h < 2; ++h)
      #pragma unroll
      for (int r = 0; r < 4; ++r)
        lacc[h][r] += __shfl_xor(lacc[h][r], o, 16);
  if (ql == 0) {
    #pragma unroll
    for (int h = 0; h < 2; ++h)
      #pragma unroll
      for (int r = 0; r < 4; ++r)
        atomicAdd(&lrow[(size_t)(qt0 + quad * 4 + r) * 2 + h], lacc[h][r]);
  }
}

// ---------------- attention pass 2: attn writes (nontemporal) + O = P@V ----------------
__global__ __launch_bounds__(256) void att_pass2(
    const unsigned short* __restrict__ qb, const unsigned short* __restrict__ kb,
    const unsigned short* __restrict__ Vt, const float* __restrict__ lrow,
    float* __restrict__ attn, float* __restrict__ O) {
  __shared__ __align__(16) float Esh[4][2][16 * 36];
  __shared__ float Osh[16 * 64];
  const int tid = threadIdx.x;
  const int lane = tid & 63, wv = tid >> 6;
  const int ql = lane & 15, quad = lane >> 4;
  const int qt0 = blockIdx.x * 16;
  const floatx4 zf = {0.f, 0.f, 0.f, 0.f};

  for (int idx = tid; idx < 16 * 64; idx += 256) Osh[idx] = 0.f;
  __syncthreads();

  short8 qf[2];
  #pragma unroll
  for (int h = 0; h < 2; ++h)
    qf[h] = *(const short8*)(qb + (size_t)(qt0 + ql) * 64 + h * 32 + quad * 8);

  float invl[2][4];
  #pragma unroll
  for (int h = 0; h < 2; ++h)
    #pragma unroll
    for (int r = 0; r < 4; ++r)
      invl[h][r] = 1.0f / lrow[(size_t)(qt0 + quad * 4 + r) * 2 + h];

  floatx4 oacc[2][2];
  #pragma unroll
  for (int h = 0; h < 2; ++h)
    #pragma unroll
    for (int hf = 0; hf < 2; ++hf) oacc[h][hf] = zf;

  int kbase = wv * 2048;
  for (int it = 0; it < 64; ++it, kbase += 32) {
    short8 kf[2][2], vf[2][2];
    #pragma unroll
    for (int kt = 0; kt < 2; ++kt)
      #pragma unroll
      for (int h = 0; h < 2; ++h)
        kf[kt][h] = *(const short8*)(kb + (size_t)(kbase + kt * 16 + ql) * 64 + h * 32 + quad * 8);
    #pragma unroll
    for (int h = 0; h < 2; ++h)
      #pragma unroll
      for (int hf = 0; hf < 2; ++hf)
        vf[h][hf] = *(const short8*)(Vt + (size_t)(h * 32 + hf * 16 + ql) * NN + kbase + quad * 8);

    floatx4 p[2][2];  // [head][kt]
    #pragma unroll
    for (int h = 0; h < 2; ++h)
      #pragma unroll
      for (int kt = 0; kt < 2; ++kt) {
        floatx4 s = __builtin_amdgcn_mfma_f32_16x16x32_bf16(qf[h], kf[kt][h], zf, 0, 0, 0);
        #pragma unroll
        for (int r = 0; r < 4; ++r)
          p[h][kt][r] = __builtin_amdgcn_exp2f(s[r]) * invl[h][r];
      }
    #pragma unroll
    for (int kt = 0; kt < 2; ++kt)
      #pragma unroll
      for (int r = 0; r < 4; ++r) {
        size_t row = (size_t)(qt0 + quad * 4 + r);
        __builtin_nontemporal_store(0.5f * (p[0][kt][r] + p[1][kt][r]),
                                    &attn[row * NN + kbase + kt * 16 + ql]);
      }
    // C-layout -> LDS -> A-layout round trip, then PV mfma
    #pragma unroll
    for (int h = 0; h < 2; ++h)
      #pragma unroll
      for (int kt = 0; kt < 2; ++kt)
        #pragma unroll
        for (int r = 0; r < 4; ++r)
          Esh[wv][h][(quad * 4 + r) * 36 + kt * 16 + ql] = p[h][kt][r];
    #pragma unroll
    for (int h = 0; h < 2; ++h) {
      const float* ep = &Esh[wv][h][ql * 36 + quad * 8];
      float4 x0 = *(const float4*)ep;
      float4 x1 = *(const float4*)(ep + 4);
      short8 ef;
      ef[0] = (short)f2bf(x0.x); ef[1] = (short)f2bf(x0.y);
      ef[2] = (short)f2bf(x0.z); ef[3] = (short)f2bf(x0.w);
      ef[4] = (short)f2bf(x1.x); ef[5] = (short)f2bf(x1.y);
      ef[6] = (short)f2bf(x1.z); ef[7] = (short)f2bf(x1.w);
      #pragma unroll
      for (int hf = 0; hf < 2; ++hf)
        oacc[h][hf] = __builtin_amdgcn_mfma_f32_16x16x32_bf16(ef, vf[h][hf], oacc[h][hf], 0, 0, 0);
    }
  }
  #pragma unroll
  for (int h = 0; h < 2; ++h)
    #pragma unroll
    for (int hf = 0; hf < 2; ++hf)
      #pragma unroll
      for (int r = 0; r < 4; ++r)
        atomicAdd(&Osh[(quad * 4 + r) * 64 + h * 32 + hf * 16 + ql], oacc[h][hf][r]);
  __syncthreads();
  for (int idx = tid; idx < 16 * 64; idx += 256)
    O[(size_t)qt0 * 64 + idx] = Osh[idx];
}

// ---------------- tail: h_attn = O@Wo+bo ; y1 = relu([htkg|h_attn]@fc1+b) ; pred = y1@fc2+b ----------------
// grid 256 x 32 rows, block 256 (rg=tid>>6 handles 8 rows, col=tid&63)
__global__ __launch_bounds__(256) void tail_k(const float* __restrict__ O,
    const float* __restrict__ htkg, const float* __restrict__ Wo, const float* __restrict__ bo,
    const float* __restrict__ fc1W, const float* __restrict__ fc1b,
    const float* __restrict__ fc2W, const float* __restrict__ fc2b,
    float* __restrict__ pred) {
  __shared__ float Ws[8192];
  __shared__ float T1[2048];
  __shared__ float T2[2048];
  const int tid = threadIdx.x;
  const int col = tid & 63, rg = tid >> 6;
  const int rowbase = blockIdx.x * 32;
  for (int i = tid; i < 2048; i += 256) T1[i] = O[(size_t)rowbase * 64 + i];
  for (int i = tid; i < 4096; i += 256) Ws[i] = Wo[i];
  const float rbo = bo[col], rf1b = fc1b[col], rf2 = fc2W[col], rf2b = fc2b[0];
  __syncthreads();
  float ha[8];
  #pragma unroll
  for (int r = 0; r < 8; ++r) {
    const int row = rg * 8 + r;
    float acc = rbo;
    for (int k = 0; k < 64; ++k) acc = fmaf(T1[row * 64 + k], Ws[k * 64 + col], acc);
    ha[r] = acc;
  }
  __syncthreads();
  #pragma unroll
  for (int r = 0; r < 8; ++r) T2[(rg * 8 + r) * 64 + col] = ha[r];
  for (int i = tid; i < 2048; i += 256) T1[i] = htkg[(size_t)rowbase * 64 + i];
  for (int i = tid; i < 8192; i += 256) Ws[i] = fc1W[i];
  __syncthreads();
  #pragma unroll
  for (int r = 0; r < 8; ++r) {
    const int row = rg * 8 + r;
    float acc = rf1b;
    for (int k = 0; k < 64; ++k) acc = fmaf(T1[row * 64 + k], Ws[k * 64 + col], acc);
    for (int k = 0; k < 64; ++k) acc = fmaf(T2[row * 64 + k], Ws[(64 + k) * 64 + col], acc);
    float y = fmaxf(acc, 0.f);
    float v = y * rf2;
    #pragma unroll
    for (int m = 32; m >= 1; m >>= 1) v += __shfl_xor(v, m);
    if (col == 0) pred[rowbase + row] = v + rf2b;
  }
}

extern "C" void kernel_launch(void* const* d_in, const int* in_sizes, int n_in,
                              void* d_out, int out_size, void* d_ws, size_t ws_size,
                              hipStream_t stream) {
  (void)in_sizes; (void)n_in; (void)out_size; (void)ws_size;
  const float* x       = (const float*)d_in[0];
  const int*   ei_t    = (const int*)d_in[1];
  const int*   ei_e    = (const int*)d_in[2];
  const float* gat1_W  = (const float*)d_in[3];
  const float* gat1_as = (const float*)d_in[4];
  const float* gat1_ad = (const float*)d_in[5];
  const float* gat1_b  = (const float*)d_in[6];
  const float* gat2_W  = (const float*)d_in[7];
  const float* gat2_as = (const float*)d_in[8];
  const float* gat2_ad = (const float*)d_in[9];
  const float* gat2_b  = (const float*)d_in[10];
  const float* gcn1_W  = (const float*)d_in[11];
  const float* gcn1_b  = (const float*)d_in[12];
  const float* gcn2_W  = (const float*)d_in[13];
  const float* gcn2_b  = (const float*)d_in[14];
  const float* Wq = (const float*)d_in[15]; const float* bq = (const float*)d_in[16];
  const float* Wk = (const float*)d_in[17]; const float* bk = (const float*)d_in[18];
  const float* Wv = (const float*)d_in[19]; const float* bv = (const float*)d_in[20];
  const float* Wo = (const float*)d_in[21]; const float* bo = (const float*)d_in[22];
  const float* fc1_W = (const float*)d_in[23]; const float* fc1_b = (const float*)d_in[24];
  const float* fc2_W = (const float*)d_in[25]; const float* fc2_b = (const float*)d_in[26];

  float* out  = (float*)d_out;
  float* attn = out + NN;   // [N, N] fp32, after pred[N]

  char* wsp = (char*)d_ws;
  size_t ofs = 0;
  auto take = [&](size_t bytes) -> char* {
    char* p = wsp + ofs;
    ofs = (ofs + bytes + 255) & ~(size_t)255;
    return p;
  };
  // ---- contiguous zero-init region first (single memset) ----
  int*   pos_t = (int*)take(NN * 4);
  int*   pos_e = (int*)take(NN * 4);
  float* lbuf  = (float*)take((size_t)NN * 2 * 4);
  float* a_s1  = (float*)take((size_t)NN * 2 * 4);
  float* a_d1  = (float*)take((size_t)NN * 2 * 4);
  float* a_s2  = (float*)take((size_t)NN * 4);
  float* a_d2  = (float*)take((size_t)NN * 4);
  const size_t zero_span = ofs;
  // ---- rest ----
  int* off_t = (int*)take((NN + 1) * 4);
  int* off_e = (int*)take((NN + 1) * 4);
  int* src_t = (int*)take((size_t)ET * 4);
  int* src_e = (int*)take((size_t)ET * 4);
  float* h1    = (float*)take((size_t)NN * 128 * 4);
  float* g1out = (float*)take((size_t)NN * 128 * 4);
  float* h2    = (float*)take((size_t)NN * 64 * 4);
  float* htkg  = (float*)take((size_t)NN * 64 * 4);
  float* hg1   = (float*)take((size_t)NN * 64 * 4);
  float* h2g   = (float*)take((size_t)NN * 64 * 4);
  float* hekg  = (float*)take((size_t)NN * 64 * 4);
  unsigned short* qb = (unsigned short*)take((size_t)NN * 64 * 2);
  unsigned short* kb = (unsigned short*)take((size_t)NN * 64 * 2);
  unsigned short* Vt = (unsigned short*)take((size_t)64 * NN * 2);
  float* Obuf  = (float*)take((size_t)NN * 64 * 4);

  hipMemsetAsync(wsp, 0, zero_span, stream);

  // CSR for both graphs (3 launches)
  edge_hist2_k<<<2 * ET / 256, 256, 0, stream>>>(ei_t, ei_e, pos_t, pos_e);
  scan2_k<<<2, 1024, 0, stream>>>(pos_t, off_t, pos_e, off_e);
  edge_scatter2_k<<<2 * ET / 256, 256, 0, stream>>>(ei_t, ei_e, pos_t, pos_e, src_t, src_e);

  // x projections for both branches + gat1 att_sd epilogue
  mm_x_k<<<dim3(128, 6), 256, 0, stream>>>(x, gat1_W, gcn1_W, gat1_as, gat1_ad,
                                           h1, hg1, a_s1, a_d1);
  // GAT branch
  gat_agg_k<2, 64><<<NN, 128, 0, stream>>>(h1, a_s1, a_d1, off_t, src_t, gat1_b, g1out, 128);
  mm_gat2_k<<<dim3(128, 2), 256, 0, stream>>>(g1out, gat2_W, gat2_as, gat2_ad, h2, a_s2, a_d2);
  gat_agg_k<1, 64><<<NN, 64, 0, stream>>>(h2, a_s2, a_d2, off_t, src_t, gat2_b, htkg, 64);

  // GCN branch (agg1 fused with gcn2 GEMV)
  gcn_agg1_k<<<NN, 64, 0, stream>>>(hg1, off_e, src_e, gcn1_b, gcn2_W, h2g);
  gcn_agg2_k<<<NN, 64, 0, stream>>>(h2g, off_e, src_e, gcn2_b, hekg);

  // qkv projections + V transpose
  mm_qkv_k<<<dim3(128, 6), 256, 0, stream>>>(htkg, hekg, Wq, bq, Wk, bk, Wv, bv, qb, kb, Vt);

  // attention
  att_pass1<<<512, 256, 0, stream>>>(qb, kb, lbuf);
  att_pass2<<<512, 256, 0, stream>>>(qb, kb, Vt, lbuf, attn, Obuf);

  // fused epilogue: Wo + fc1 + fc2
  tail_k<<<256, 256, 0, stream>>>(Obuf, htkg, Wo, bo, fc1_W, fc1_b, fc2_W, fc2_b, out);
}

// Round 3
// 668.814 us; speedup vs baseline: 1.1249x; 1.0001x over previous
//
#include <hip/hip_runtime.h>
#include <cstdint>
#include <cstddef>

#define NN 8192
#define EE 262144
#define ET 270336   // EE + NN self loops

using short8  = __attribute__((ext_vector_type(8))) short;
using floatx4 = __attribute__((ext_vector_type(4))) float;

__device__ __forceinline__ unsigned short f2bf(float f) {
  unsigned int u = __float_as_uint(f);
  u += 0x7fffu + ((u >> 16) & 1u);          // RNE
  return (unsigned short)(u >> 16);
}

// ---------------- CSR build, both graphs in one launch ----------------
__global__ void edge_hist2_k(const int* __restrict__ ei_t, const int* __restrict__ ei_e,
                             int* __restrict__ cnt_t, int* __restrict__ cnt_e) {
  int idx = blockIdx.x * 256 + threadIdx.x;
  int g = idx >= ET;                        // block-uniform (ET % 256 == 0)
  int e = g ? idx - ET : idx;
  const int* ei = g ? ei_e : ei_t;
  int* cnt = g ? cnt_e : cnt_t;
  int d = (e < EE) ? ei[EE + e] : (e - EE);
  atomicAdd(&cnt[d], 1);
}

__global__ void scan2_k(int* cnt_t, int* off_t, int* cnt_e, int* off_e) {
  int* cnt = blockIdx.x ? cnt_e : cnt_t;    // pos aliases cnt (overwritten)
  int* off = blockIdx.x ? off_e : off_t;
  __shared__ int s[1024];
  int t = threadIdx.x;
  int v[8]; int base = t * 8; int sum = 0;
  #pragma unroll
  for (int j = 0; j < 8; ++j) { v[j] = cnt[base + j]; sum += v[j]; }
  s[t] = sum; __syncthreads();
  for (int o = 1; o < 1024; o <<= 1) {
    int x = (t >= o) ? s[t - o] : 0;
    __syncthreads();
    s[t] += x;
    __syncthreads();
  }
  int excl = s[t] - sum;
  #pragma unroll
  for (int j = 0; j < 8; ++j) { off[base + j] = excl; cnt[base + j] = excl; excl += v[j]; }
  if (t == 1023) off[NN] = excl;
}

__global__ void edge_scatter2_k(const int* __restrict__ ei_t, const int* __restrict__ ei_e,
                                int* __restrict__ pos_t, int* __restrict__ pos_e,
                                int* __restrict__ srcs_t, int* __restrict__ srcs_e) {
  int idx = blockIdx.x * 256 + threadIdx.x;
  int g = idx >= ET;
  int e = g ? idx - ET : idx;
  const int* ei = g ? ei_e : ei_t;
  int* pos = g ? pos_e : pos_t;
  int* srcs = g ? srcs_e : srcs_t;
  int sv, d;
  if (e < EE) { sv = ei[e]; d = ei[EE + e]; } else { sv = d = e - EE; }
  int p = atomicAdd(&pos[d], 1);
  srcs[p] = sv;
}

// ---------------- shared GEMM inner loop ----------------
__device__ __forceinline__ void gemm_core(const float* __restrict__ A, int lda, int K,
                                          const float* __restrict__ Bs, int row0, int col,
                                          float acc[8]) {
  #pragma unroll
  for (int r = 0; r < 8; ++r) acc[r] = 0.f;
  for (int k = 0; k < K; k += 4) {
    float b0 = Bs[(k + 0) * 32 + col], b1 = Bs[(k + 1) * 32 + col];
    float b2 = Bs[(k + 2) * 32 + col], b3 = Bs[(k + 3) * 32 + col];
    #pragma unroll
    for (int r = 0; r < 8; ++r) {
      const float4 a4 = *(const float4*)(A + (size_t)(row0 + r) * lda + k);
      acc[r] = fmaf(a4.x, b0, acc[r]);
      acc[r] = fmaf(a4.y, b1, acc[r]);
      acc[r] = fmaf(a4.z, b2, acc[r]);
      acc[r] = fmaf(a4.w, b3, acc[r]);
    }
  }
}

// ---------------- mm_x: h1 = x@gat1_W (+att_sd epilogue), hg1 = x@gcn1_W ----------------
__global__ __launch_bounds__(256) void mm_x_k(const float* __restrict__ x,
    const float* __restrict__ Wgat, const float* __restrict__ Wgcn,
    const float* __restrict__ as_w, const float* __restrict__ ad_w,
    float* __restrict__ h1, float* __restrict__ hg1,
    float* __restrict__ a_s1, float* __restrict__ a_d1) {
  __shared__ float Bs[256 * 32];
  const int tid = threadIdx.x, by = blockIdx.y;
  const bool gat = by < 4;
  const int NC = gat ? 128 : 64;
  const int c0 = gat ? by * 32 : (by - 4) * 32;
  const float* B = gat ? Wgat : Wgcn;
  for (int idx = tid; idx < 256 * 32; idx += 256)
    Bs[idx] = B[(idx >> 5) * NC + c0 + (idx & 31)];
  __syncthreads();
  const int row0 = blockIdx.x * 64 + (tid >> 5) * 8;
  const int col = tid & 31;
  float acc[8];
  gemm_core(x, 256, 256, Bs, row0, col, acc);
  if (gat) {
    #pragma unroll
    for (int r = 0; r < 8; ++r) h1[(size_t)(row0 + r) * 128 + c0 + col] = acc[r];
    const int head = c0 >> 6;
    const float asw = as_w[head * 64 + (c0 & 63) + col];
    const float adw = ad_w[head * 64 + (c0 & 63) + col];
    float ps[8], pd[8];
    #pragma unroll
    for (int r = 0; r < 8; ++r) { ps[r] = acc[r] * asw; pd[r] = acc[r] * adw; }
    #pragma unroll
    for (int m = 16; m >= 1; m >>= 1)
      #pragma unroll
      for (int r = 0; r < 8; ++r) { ps[r] += __shfl_xor(ps[r], m); pd[r] += __shfl_xor(pd[r], m); }
    if (col == 0) {
      #pragma unroll
      for (int r = 0; r < 8; ++r) {
        atomicAdd(&a_s1[(row0 + r) * 2 + head], ps[r]);
        atomicAdd(&a_d1[(row0 + r) * 2 + head], pd[r]);
      }
    }
  } else {
    #pragma unroll
    for (int r = 0; r < 8; ++r) hg1[(size_t)(row0 + r) * 64 + c0 + col] = acc[r];
  }
}

// ---------------- GAT aggregation (template, used standalone for layer 2) ----------------
template<int H, int C>
__device__ __forceinline__ void gat_agg_body(const float* __restrict__ h,
    const float* __restrict__ a_s, const float* __restrict__ a_d,
    const int* __restrict__ off, const int* __restrict__ srcs,
    const float* __restrict__ bias, float* __restrict__ out, int ldout, int b) {
  constexpr int HC = H * C;
  const int tid = threadIdx.x;
  const int hd = tid / C;
  const int r0 = off[b], r1 = off[b + 1];
  __shared__ int s_src[HC];
  __shared__ float s_w[HC][H];
  float ad[H];
  #pragma unroll
  for (int hh = 0; hh < H; ++hh) ad[hh] = a_d[b * H + hh];
  float acc = 0.f, den = 0.f;
  for (int base = r0; base < r1; base += HC) {
    __syncthreads();
    int e = base + tid;
    if (e < r1) {
      int sv = srcs[e];
      s_src[tid] = sv;
      #pragma unroll
      for (int hh = 0; hh < H; ++hh) {
        float xv = a_s[sv * H + hh] + ad[hh];
        xv = xv > 0.f ? xv : 0.2f * xv;     // leaky_relu 0.2
        s_w[tid][hh] = __expf(xv);
      }
    }
    __syncthreads();
    int cnt = min(HC, r1 - base);
    for (int j = 0; j < cnt; ++j) {
      float wv = s_w[j][hd];
      den += wv;
      acc = fmaf(wv, h[(size_t)s_src[j] * HC + tid], acc);
    }
  }
  float o = acc / den + bias[tid];
  out[(size_t)b * ldout + tid] = o > 0.f ? o : (__expf(o) - 1.f);  // elu
}

template<int H, int C>
__global__ void gat_agg_k(const float* __restrict__ h, const float* __restrict__ a_s,
                          const float* __restrict__ a_d, const int* __restrict__ off,
                          const int* __restrict__ srcs, const float* __restrict__ bias,
                          float* __restrict__ out, int ldout) {
  gat_agg_body<H, C>(h, a_s, a_d, off, srcs, bias, out, ldout, blockIdx.x);
}

// ---------------- merged: gat1 aggregation (blocks 0..NN) + gcn1 agg+gemv (2 nodes/blk) ----
__global__ __launch_bounds__(128) void agg1_k(
    const float* __restrict__ h1, const float* __restrict__ a_s1, const float* __restrict__ a_d1,
    const int* __restrict__ off_t, const int* __restrict__ src_t,
    const float* __restrict__ gat1_b, float* __restrict__ g1out,
    const float* __restrict__ hg1, const int* __restrict__ off_e, const int* __restrict__ src_e,
    const float* __restrict__ gcn1_b, const float* __restrict__ gcn2_W, float* __restrict__ h2g) {
  const int tid = threadIdx.x;
  if (blockIdx.x < NN) {
    gat_agg_body<2, 64>(h1, a_s1, a_d1, off_t, src_t, gat1_b, g1out, 128, blockIdx.x);
  } else {
    const int nb = (blockIdx.x - NN) * 2;
    const int sub = tid >> 6, t = tid & 63;
    const int node = nb + sub;
    __shared__ int s_src2[2][64];
    __shared__ float s_nrm2[2][64];
    __shared__ float s_row2[2][64];
    const int r0 = off_e[node], r1 = off_e[node + 1];
    const int cA = off_e[nb + 1] - off_e[nb];
    const int cB = off_e[nb + 2] - off_e[nb + 1];
    const int trips = (max(cA, cB) + 63) >> 6;
    float dinv_b = rsqrtf((float)max(r1 - r0, 1));
    float acc = 0.f;
    for (int it = 0; it < trips; ++it) {
      __syncthreads();
      int e = r0 + it * 64 + t;
      if (e < r1) {
        int sv = src_e[e];
        s_src2[sub][t] = sv;
        int ds = off_e[sv + 1] - off_e[sv];
        s_nrm2[sub][t] = dinv_b * rsqrtf((float)max(ds, 1));
      }
      __syncthreads();
      int cnt = min(64, r1 - (r0 + it * 64));
      for (int j = 0; j < cnt; ++j)
        acc = fmaf(s_nrm2[sub][j], hg1[(size_t)s_src2[sub][j] * 64 + t], acc);
    }
    s_row2[sub][t] = fmaxf(acc + gcn1_b[t], 0.f);
    __syncthreads();
    float acc2 = 0.f;
    for (int k = 0; k < 64; ++k)
      acc2 = fmaf(s_row2[sub][k], gcn2_W[k * 64 + t], acc2);
    h2g[(size_t)node * 64 + t] = acc2;
  }
}

// ---------------- merged: mm_gat2 (blocks 0..256) + gcn_agg2 (4 nodes/blk) ----------------
__global__ __launch_bounds__(256) void mm2_k(
    const float* __restrict__ g1out, const float* __restrict__ gat2_W,
    const float* __restrict__ gat2_as, const float* __restrict__ gat2_ad,
    float* __restrict__ h2, float* __restrict__ a_s2, float* __restrict__ a_d2,
    const float* __restrict__ h2g, const int* __restrict__ off_e, const int* __restrict__ src_e,
    const float* __restrict__ gcn2_b, float* __restrict__ hekg) {
  const int tid = threadIdx.x;
  if (blockIdx.x < 256) {
    __shared__ float Bs[128 * 32];
    const int bx = blockIdx.x & 127;
    const int c0 = (blockIdx.x >> 7) * 32;
    for (int idx = tid; idx < 128 * 32; idx += 256)
      Bs[idx] = gat2_W[(idx >> 5) * 64 + c0 + (idx & 31)];
    __syncthreads();
    const int row0 = bx * 64 + (tid >> 5) * 8;
    const int col = tid & 31;
    float acc[8];
    gemm_core(g1out, 128, 128, Bs, row0, col, acc);
    const float asw = gat2_as[c0 + col];
    const float adw = gat2_ad[c0 + col];
    float ps[8], pd[8];
    #pragma unroll
    for (int r = 0; r < 8; ++r) {
      h2[(size_t)(row0 + r) * 64 + c0 + col] = acc[r];
      ps[r] = acc[r] * asw; pd[r] = acc[r] * adw;
    }
    #pragma unroll
    for (int m = 16; m >= 1; m >>= 1)
      #pragma unroll
      for (int r = 0; r < 8; ++r) { ps[r] += __shfl_xor(ps[r], m); pd[r] += __shfl_xor(pd[r], m); }
    if (col == 0) {
      #pragma unroll
      for (int r = 0; r < 8; ++r) {
        atomicAdd(&a_s2[row0 + r], ps[r]);
        atomicAdd(&a_d2[row0 + r], pd[r]);
      }
    }
  } else {
    const int nb = (blockIdx.x - 256) * 4;
    const int sub = tid >> 6, t = tid & 63;
    const int node = nb + sub;
    __shared__ int s_src4[4][64];
    __shared__ float s_nrm4[4][64];
    const int r0 = off_e[node], r1 = off_e[node + 1];
    int cmax = 0;
    #pragma unroll
    for (int i = 0; i < 4; ++i) cmax = max(cmax, off_e[nb + i + 1] - off_e[nb + i]);
    const int trips = (cmax + 63) >> 6;
    float dinv_b = rsqrtf((float)max(r1 - r0, 1));
    float acc = 0.f;
    for (int it = 0; it < trips; ++it) {
      __syncthreads();
      int e = r0 + it * 64 + t;
      if (e < r1) {
        int sv = src_e[e];
        s_src4[sub][t] = sv;
        int ds = off_e[sv + 1] - off_e[sv];
        s_nrm4[sub][t] = dinv_b * rsqrtf((float)max(ds, 1));
      }
      __syncthreads();
      int cnt = min(64, r1 - (r0 + it * 64));
      for (int j = 0; j < cnt; ++j)
        acc = fmaf(s_nrm4[sub][j], h2g[(size_t)s_src4[sub][j] * 64 + t], acc);
    }
    hekg[(size_t)node * 64 + t] = fmaxf(acc + gcn2_b[t], 0.f);
  }
}

// ---------------- qkv projections (+V transpose) ----------------
__global__ __launch_bounds__(256) void mm_qkv_k(const float* __restrict__ htkg,
    const float* __restrict__ hekg,
    const float* __restrict__ Wq, const float* __restrict__ bq,
    const float* __restrict__ Wk, const float* __restrict__ bk,
    const float* __restrict__ Wv, const float* __restrict__ bv,
    unsigned short* __restrict__ qb, unsigned short* __restrict__ kb,
    unsigned short* __restrict__ Vt) {
  __shared__ float Bs[64 * 32];
  __shared__ float Ts[32][65];
  const int tid = threadIdx.x, by = blockIdx.y;
  const int kind = by >> 1;
  const int c0 = (by & 1) * 32;
  const float* A = (kind == 0) ? htkg : hekg;
  const float* B = (kind == 0) ? Wq : (kind == 1) ? Wk : Wv;
  const float* bias = (kind == 0) ? bq : (kind == 1) ? bk : bv;
  for (int idx = tid; idx < 64 * 32; idx += 256)
    Bs[idx] = B[(idx >> 5) * 64 + c0 + (idx & 31)];
  __syncthreads();
  const int row0 = blockIdx.x * 64 + (tid >> 5) * 8;
  const int col = tid & 31;
  float acc[8];
  gemm_core(A, 64, 64, Bs, row0, col, acc);
  const float bb = bias[c0 + col];
  if (kind == 0) {
    const float SCL = 0.17677669529663687f * 1.4426950408889634f;  // 1/sqrt(32) * log2(e)
    #pragma unroll
    for (int r = 0; r < 8; ++r)
      qb[(size_t)(row0 + r) * 64 + c0 + col] = f2bf((acc[r] + bb) * SCL);
  } else if (kind == 1) {
    #pragma unroll
    for (int r = 0; r < 8; ++r)
      kb[(size_t)(row0 + r) * 64 + c0 + col] = f2bf(acc[r] + bb);
  } else {
    const int rl = (tid >> 5) * 8;
    #pragma unroll
    for (int r = 0; r < 8; ++r) Ts[col][rl + r] = acc[r] + bb;
    __syncthreads();
    const int c = tid >> 3, rr = (tid & 7) * 8;
    short8 pk;
    #pragma unroll
    for (int j = 0; j < 8; ++j) pk[j] = (short)f2bf(Ts[c][rr + j]);
    *(short8*)(Vt + (size_t)(c0 + c) * NN + blockIdx.x * 64 + rr) = pk;
  }
}

// ---------------- attention pass 1: lrow[q][h] = sum_k exp2(s) ----------------
// grid 1024: (qtile, K-half). wave strip = 1024 keys. 4 blocks/CU.
__global__ __launch_bounds__(256, 4) void att_pass1(const unsigned short* __restrict__ qb,
                                                    const unsigned short* __restrict__ kb,
                                                    float* __restrict__ lrow) {
  const int tid = threadIdx.x;
  const int lane = tid & 63, wv = tid >> 6;
  const int ql = lane & 15, quad = lane >> 4;
  const int qt0 = (blockIdx.x >> 1) * 16;
  const int khalf = blockIdx.x & 1;
  const floatx4 zf = {0.f, 0.f, 0.f, 0.f};
  short8 qf[2];
  #pragma unroll
  for (int h = 0; h < 2; ++h)
    qf[h] = *(const short8*)(qb + (size_t)(qt0 + ql) * 64 + h * 32 + quad * 8);
  float lacc[2][4];
  #pragma unroll
  for (int h = 0; h < 2; ++h)
    #pragma unroll
    for (int r = 0; r < 4; ++r) lacc[h][r] = 0.f;
  int kbase = khalf * 4096 + wv * 1024;
  for (int it = 0; it < 32; ++it, kbase += 32) {
    short8 kf[2][2];
    #pragma unroll
    for (int kt = 0; kt < 2; ++kt)
      #pragma unroll
      for (int h = 0; h < 2; ++h)
        kf[kt][h] = *(const short8*)(kb + (size_t)(kbase + kt * 16 + ql) * 64 + h * 32 + quad * 8);
    #pragma unroll
    for (int h = 0; h < 2; ++h)
      #pragma unroll
      for (int kt = 0; kt < 2; ++kt) {
        floatx4 s = __builtin_amdgcn_mfma_f32_16x16x32_bf16(qf[h], kf[kt][h], zf, 0, 0, 0);
        #pragma unroll
        for (int r = 0; r < 4; ++r) lacc[h][r] += __builtin_amdgcn_exp2f(s[r]);
      }
  }
  #pragma unroll
  for (int o = 8; o >= 1; o >>= 1)
    #pragma unroll
    for (int h = 0; h < 2; ++h)
      #pragma unroll
      for (int r = 0; r < 4; ++r)
        lacc[h][r] += __shfl_xor(lacc[h][r], o, 16);
  if (ql == 0) {
    #pragma unroll
    for (int h = 0; h < 2; ++h)
      #pragma unroll
      for (int r = 0; r < 4; ++r)
        atomicAdd(&lrow[(size_t)(qt0 + quad * 4 + r) * 2 + h], lacc[h][r]);
  }
}

// ---------------- attention pass 2: attn writes (nontemporal) + partial O = P@V ----------
__global__ __launch_bounds__(256, 4) void att_pass2(
    const unsigned short* __restrict__ qb, const unsigned short* __restrict__ kb,
    const unsigned short* __restrict__ Vt, const float* __restrict__ lrow,
    float* __restrict__ attn, float* __restrict__ Opart) {
  __shared__ __align__(16) float Esh[4][2][16 * 36];
  __shared__ float Osh[16 * 64];
  const int tid = threadIdx.x;
  const int lane = tid & 63, wv = tid >> 6;
  const int ql = lane & 15, quad = lane >> 4;
  const int qt0 = (blockIdx.x >> 1) * 16;
  const int khalf = blockIdx.x & 1;
  float* O = Opart + (size_t)khalf * NN * 64;
  const floatx4 zf = {0.f, 0.f, 0.f, 0.f};

  for (int idx = tid; idx < 16 * 64; idx += 256) Osh[idx] = 0.f;
  __syncthreads();

  short8 qf[2];
  #pragma unroll
  for (int h = 0; h < 2; ++h)
    qf[h] = *(const short8*)(qb + (size_t)(qt0 + ql) * 64 + h * 32 + quad * 8);

  float invl[2][4];
  #pragma unroll
  for (int h = 0; h < 2; ++h)
    #pragma unroll
    for (int r = 0; r < 4; ++r)
      invl[h][r] = 1.0f / lrow[(size_t)(qt0 + quad * 4 + r) * 2 + h];

  floatx4 oacc[2][2];
  #pragma unroll
  for (int h = 0; h < 2; ++h)
    #pragma unroll
    for (int hf = 0; hf < 2; ++hf) oacc[h][hf] = zf;

  int kbase = khalf * 4096 + wv * 1024;
  for (int it = 0; it < 32; ++it, kbase += 32) {
    short8 kf[2][2], vf[2][2];
    #pragma unroll
    for (int kt = 0; kt < 2; ++kt)
      #pragma unroll
      for (int h = 0; h < 2; ++h)
        kf[kt][h] = *(const short8*)(kb + (size_t)(kbase + kt * 16 + ql) * 64 + h * 32 + quad * 8);
    #pragma unroll
    for (int h = 0; h < 2; ++h)
      #pragma unroll
      for (int hf = 0; hf < 2; ++hf)
        vf[h][hf] = *(const short8*)(Vt + (size_t)(h * 32 + hf * 16 + ql) * NN + kbase + quad * 8);

    floatx4 p[2][2];  // [head][kt]
    #pragma unroll
    for (int h = 0; h < 2; ++h)
      #pragma unroll
      for (int kt = 0; kt < 2; ++kt) {
        floatx4 s = __builtin_amdgcn_mfma_f32_16x16x32_bf16(qf[h], kf[kt][h], zf, 0, 0, 0);
        #pragma unroll
        for (int r = 0; r < 4; ++r)
          p[h][kt][r] = __builtin_amdgcn_exp2f(s[r]) * invl[h][r];
      }
    #pragma unroll
    for (int kt = 0; kt < 2; ++kt)
      #pragma unroll
      for (int r = 0; r < 4; ++r) {
        size_t row = (size_t)(qt0 + quad * 4 + r);
        __builtin_nontemporal_store(0.5f * (p[0][kt][r] + p[1][kt][r]),
                                    &attn[row * NN + kbase + kt * 16 + ql]);
      }
    // C-layout -> LDS -> A-layout round trip, then PV mfma
    #pragma unroll
    for (int h = 0; h < 2; ++h)
      #pragma unroll
      for (int kt = 0; kt < 2; ++kt)
        #pragma unroll
        for (int r = 0; r < 4; ++r)
          Esh[wv][h][(quad * 4 + r) * 36 + kt * 16 + ql] = p[h][kt][r];
    #pragma unroll
    for (int h = 0; h < 2; ++h) {
      const float* ep = &Esh[wv][h][ql * 36 + quad * 8];
      float4 x0 = *(const float4*)ep;
      float4 x1 = *(const float4*)(ep + 4);
      short8 ef;
      ef[0] = (short)f2bf(x0.x); ef[1] = (short)f2bf(x0.y);
      ef[2] = (short)f2bf(x0.z); ef[3] = (short)f2bf(x0.w);
      ef[4] = (short)f2bf(x1.x); ef[5] = (short)f2bf(x1.y);
      ef[6] = (short)f2bf(x1.z); ef[7] = (short)f2bf(x1.w);
      #pragma unroll
      for (int hf = 0; hf < 2; ++hf)
        oacc[h][hf] = __builtin_amdgcn_mfma_f32_16x16x32_bf16(ef, vf[h][hf], oacc[h][hf], 0, 0, 0);
    }
  }
  #pragma unroll
  for (int h = 0; h < 2; ++h)
    #pragma unroll
    for (int hf = 0; hf < 2; ++hf)
      #pragma unroll
      for (int r = 0; r < 4; ++r)
        atomicAdd(&Osh[(quad * 4 + r) * 64 + h * 32 + hf * 16 + ql], oacc[h][hf][r]);
  __syncthreads();
  for (int idx = tid; idx < 16 * 64; idx += 256)
    O[(size_t)qt0 * 64 + idx] = Osh[idx];
}

// ---------------- tail: h_attn=(O1+O2)@Wo+bo ; y1=relu([htkg|h_attn]@fc1+b) ; pred=y1@fc2+b --
__global__ __launch_bounds__(256) void tail_k(const float* __restrict__ Opart,
    const float* __restrict__ htkg, const float* __restrict__ Wo, const float* __restrict__ bo,
    const float* __restrict__ fc1W, const float* __restrict__ fc1b,
    const float* __restrict__ fc2W, const float* __restrict__ fc2b,
    float* __restrict__ pred) {
  __shared__ float Ws[8192];
  __shared__ float T1[2048];
  __shared__ float T2[2048];
  const int tid = threadIdx.x;
  const int col = tid & 63, rg = tid >> 6;
  const int rowbase = blockIdx.x * 32;
  for (int i = tid; i < 2048; i += 256) {
    size_t idx = (size_t)rowbase * 64 + i;
    T1[i] = Opart[idx] + Opart[(size_t)NN * 64 + idx];
  }
  for (int i = tid; i < 4096; i += 256) Ws[i] = Wo[i];
  const float rbo = bo[col], rf1b = fc1b[col], rf2 = fc2W[col], rf2b = fc2b[0];
  __syncthreads();
  float ha[8];
  #pragma unroll
  for (int r = 0; r < 8; ++r) {
    const int row = rg * 8 + r;
    float acc = rbo;
    for (int k = 0; k < 64; ++k) acc = fmaf(T1[row * 64 + k], Ws[k * 64 + col], acc);
    ha[r] = acc;
  }
  __syncthreads();
  #pragma unroll
  for (int r = 0; r < 8; ++r) T2[(rg * 8 + r) * 64 + col] = ha[r];
  for (int i = tid; i < 2048; i += 256) T1[i] = htkg[(size_t)rowbase * 64 + i];
  for (int i = tid; i < 8192; i += 256) Ws[i] = fc1W[i];
  __syncthreads();
  #pragma unroll
  for (int r = 0; r < 8; ++r) {
    const int row = rg * 8 + r;
    float acc = rf1b;
    for (int k = 0; k < 64; ++k) acc = fmaf(T1[row * 64 + k], Ws[k * 64 + col], acc);
    for (int k = 0; k < 64; ++k) acc = fmaf(T2[row * 64 + k], Ws[(64 + k) * 64 + col], acc);
    float y = fmaxf(acc, 0.f);
    float v = y * rf2;
    #pragma unroll
    for (int m = 32; m >= 1; m >>= 1) v += __shfl_xor(v, m);
    if (col == 0) pred[rowbase + row] = v + rf2b;
  }
}

extern "C" void kernel_launch(void* const* d_in, const int* in_sizes, int n_in,
                              void* d_out, int out_size, void* d_ws, size_t ws_size,
                              hipStream_t stream) {
  (void)in_sizes; (void)n_in; (void)out_size; (void)ws_size;
  const float* x       = (const float*)d_in[0];
  const int*   ei_t    = (const int*)d_in[1];
  const int*   ei_e    = (const int*)d_in[2];
  const float* gat1_W  = (const float*)d_in[3];
  const float* gat1_as = (const float*)d_in[4];
  const float* gat1_ad = (const float*)d_in[5];
  const float* gat1_b  = (const float*)d_in[6];
  const float* gat2_W  = (const float*)d_in[7];
  const float* gat2_as = (const float*)d_in[8];
  const float* gat2_ad = (const float*)d_in[9];
  const float* gat2_b  = (const float*)d_in[10];
  const float* gcn1_W  = (const float*)d_in[11];
  const float* gcn1_b  = (const float*)d_in[12];
  const float* gcn2_W  = (const float*)d_in[13];
  const float* gcn2_b  = (const float*)d_in[14];
  const float* Wq = (const float*)d_in[15]; const float* bq = (const float*)d_in[16];
  const float* Wk = (const float*)d_in[17]; const float* bk = (const float*)d_in[18];
  const float* Wv = (const float*)d_in[19]; const float* bv = (const float*)d_in[20];
  const float* Wo = (const float*)d_in[21]; const float* bo = (const float*)d_in[22];
  const float* fc1_W = (const float*)d_in[23]; const float* fc1_b = (const float*)d_in[24];
  const float* fc2_W = (const float*)d_in[25]; const float* fc2_b = (const float*)d_in[26];

  float* out  = (float*)d_out;
  float* attn = out + NN;   // [N, N] fp32, after pred[N]

  char* wsp = (char*)d_ws;
  size_t ofs = 0;
  auto take = [&](size_t bytes) -> char* {
    char* p = wsp + ofs;
    ofs = (ofs + bytes + 255) & ~(size_t)255;
    return p;
  };
  // ---- contiguous zero-init region first (single memset) ----
  int*   pos_t = (int*)take(NN * 4);
  int*   pos_e = (int*)take(NN * 4);
  float* lbuf  = (float*)take((size_t)NN * 2 * 4);
  float* a_s1  = (float*)take((size_t)NN * 2 * 4);
  float* a_d1  = (float*)take((size_t)NN * 2 * 4);
  float* a_s2  = (float*)take((size_t)NN * 4);
  float* a_d2  = (float*)take((size_t)NN * 4);
  const size_t zero_span = ofs;
  // ---- rest ----
  int* off_t = (int*)take((NN + 1) * 4);
  int* off_e = (int*)take((NN + 1) * 4);
  int* src_t = (int*)take((size_t)ET * 4);
  int* src_e = (int*)take((size_t)ET * 4);
  float* h1    = (float*)take((size_t)NN * 128 * 4);
  float* g1out = (float*)take((size_t)NN * 128 * 4);
  float* h2    = (float*)take((size_t)NN * 64 * 4);
  float* htkg  = (float*)take((size_t)NN * 64 * 4);
  float* hg1   = (float*)take((size_t)NN * 64 * 4);
  float* h2g   = (float*)take((size_t)NN * 64 * 4);
  float* hekg  = (float*)take((size_t)NN * 64 * 4);
  unsigned short* qb = (unsigned short*)take((size_t)NN * 64 * 2);
  unsigned short* kb = (unsigned short*)take((size_t)NN * 64 * 2);
  unsigned short* Vt = (unsigned short*)take((size_t)64 * NN * 2);
  float* Opart = (float*)take((size_t)2 * NN * 64 * 4);

  hipMemsetAsync(wsp, 0, zero_span, stream);

  // CSR for both graphs
  edge_hist2_k<<<2 * ET / 256, 256, 0, stream>>>(ei_t, ei_e, pos_t, pos_e);
  scan2_k<<<2, 1024, 0, stream>>>(pos_t, off_t, pos_e, off_e);
  edge_scatter2_k<<<2 * ET / 256, 256, 0, stream>>>(ei_t, ei_e, pos_t, pos_e, src_t, src_e);

  // x projections for both branches + gat1 att_sd epilogue
  mm_x_k<<<dim3(128, 6), 256, 0, stream>>>(x, gat1_W, gcn1_W, gat1_as, gat1_ad,
                                           h1, hg1, a_s1, a_d1);
  // merged gat1-agg + gcn1-agg+gemv
  agg1_k<<<NN + NN / 2, 128, 0, stream>>>(h1, a_s1, a_d1, off_t, src_t, gat1_b, g1out,
                                          hg1, off_e, src_e, gcn1_b, gcn2_W, h2g);
  // merged mm_gat2 + gcn_agg2
  mm2_k<<<256 + NN / 4, 256, 0, stream>>>(g1out, gat2_W, gat2_as, gat2_ad, h2, a_s2, a_d2,
                                          h2g, off_e, src_e, gcn2_b, hekg);
  // gat layer-2 aggregation
  gat_agg_k<1, 64><<<NN, 64, 0, stream>>>(h2, a_s2, a_d2, off_t, src_t, gat2_b, htkg, 64);

  // qkv projections + V transpose
  mm_qkv_k<<<dim3(128, 6), 256, 0, stream>>>(htkg, hekg, Wq, bq, Wk, bk, Wv, bv, qb, kb, Vt);

  // attention (K-split for occupancy: 1024 blocks = 4/CU)
  att_pass1<<<1024, 256, 0, stream>>>(qb, kb, lbuf);
  att_pass2<<<1024, 256, 0, stream>>>(qb, kb, Vt, lbuf, attn, Opart);

  // fused epilogue: Wo + fc1 + fc2
  tail_k<<<256, 256, 0, stream>>>(Opart, htkg, Wo, bo, fc1_W, fc1_b, fc2_W, fc2_b, out);
}

// Round 4
// 662.057 us; speedup vs baseline: 1.1363x; 1.0102x over previous
//
#include <hip/hip_runtime.h>
#include <cstdint>
#include <cstddef>

#define NN 8192
#define EE 262144
#define ET 270336   // EE + NN self loops

using short8  = __attribute__((ext_vector_type(8))) short;
using floatx4 = __attribute__((ext_vector_type(4))) float;

__device__ __forceinline__ unsigned short f2bf(float f) {
  unsigned int u = __float_as_uint(f);
  u += 0x7fffu + ((u >> 16) & 1u);          // RNE
  return (unsigned short)(u >> 16);
}

// ---------------- CSR build, both graphs in one launch ----------------
__global__ void edge_hist2_k(const int* __restrict__ ei_t, const int* __restrict__ ei_e,
                             int* __restrict__ cnt_t, int* __restrict__ cnt_e) {
  int idx = blockIdx.x * 256 + threadIdx.x;
  int g = idx >= ET;                        // block-uniform (ET % 256 == 0)
  int e = g ? idx - ET : idx;
  const int* ei = g ? ei_e : ei_t;
  int* cnt = g ? cnt_e : cnt_t;
  int d = (e < EE) ? ei[EE + e] : (e - EE);
  atomicAdd(&cnt[d], 1);
}

__global__ void scan2_k(int* cnt_t, int* off_t, int* cnt_e, int* off_e) {
  int* cnt = blockIdx.x ? cnt_e : cnt_t;    // pos aliases cnt (overwritten)
  int* off = blockIdx.x ? off_e : off_t;
  __shared__ int s[1024];
  int t = threadIdx.x;
  int v[8]; int base = t * 8; int sum = 0;
  #pragma unroll
  for (int j = 0; j < 8; ++j) { v[j] = cnt[base + j]; sum += v[j]; }
  s[t] = sum; __syncthreads();
  for (int o = 1; o < 1024; o <<= 1) {
    int x = (t >= o) ? s[t - o] : 0;
    __syncthreads();
    s[t] += x;
    __syncthreads();
  }
  int excl = s[t] - sum;
  #pragma unroll
  for (int j = 0; j < 8; ++j) { off[base + j] = excl; cnt[base + j] = excl; excl += v[j]; }
  if (t == 1023) off[NN] = excl;
}

__global__ void edge_scatter2_k(const int* __restrict__ ei_t, const int* __restrict__ ei_e,
                                int* __restrict__ pos_t, int* __restrict__ pos_e,
                                int* __restrict__ srcs_t, int* __restrict__ srcs_e) {
  int idx = blockIdx.x * 256 + threadIdx.x;
  int g = idx >= ET;
  int e = g ? idx - ET : idx;
  const int* ei = g ? ei_e : ei_t;
  int* pos = g ? pos_e : pos_t;
  int* srcs = g ? srcs_e : srcs_t;
  int sv, d;
  if (e < EE) { sv = ei[e]; d = ei[EE + e]; } else { sv = d = e - EE; }
  int p = atomicAdd(&pos[d], 1);
  srcs[p] = sv;
}

// ---------------- shared GEMM inner loop ----------------
__device__ __forceinline__ void gemm_core(const float* __restrict__ A, int lda, int K,
                                          const float* __restrict__ Bs, int row0, int col,
                                          float acc[8]) {
  #pragma unroll
  for (int r = 0; r < 8; ++r) acc[r] = 0.f;
  for (int k = 0; k < K; k += 4) {
    float b0 = Bs[(k + 0) * 32 + col], b1 = Bs[(k + 1) * 32 + col];
    float b2 = Bs[(k + 2) * 32 + col], b3 = Bs[(k + 3) * 32 + col];
    #pragma unroll
    for (int r = 0; r < 8; ++r) {
      const float4 a4 = *(const float4*)(A + (size_t)(row0 + r) * lda + k);
      acc[r] = fmaf(a4.x, b0, acc[r]);
      acc[r] = fmaf(a4.y, b1, acc[r]);
      acc[r] = fmaf(a4.z, b2, acc[r]);
      acc[r] = fmaf(a4.w, b3, acc[r]);
    }
  }
}

// ---------------- mm_x: h1 = x@gat1_W (+att_sd epilogue), hg1 = x@gcn1_W ----------------
__global__ __launch_bounds__(256) void mm_x_k(const float* __restrict__ x,
    const float* __restrict__ Wgat, const float* __restrict__ Wgcn,
    const float* __restrict__ as_w, const float* __restrict__ ad_w,
    float* __restrict__ h1, float* __restrict__ hg1,
    float* __restrict__ a_s1, float* __restrict__ a_d1) {
  __shared__ float Bs[256 * 32];
  const int tid = threadIdx.x, by = blockIdx.y;
  const bool gat = by < 4;
  const int NC = gat ? 128 : 64;
  const int c0 = gat ? by * 32 : (by - 4) * 32;
  const float* B = gat ? Wgat : Wgcn;
  for (int idx = tid; idx < 256 * 32; idx += 256)
    Bs[idx] = B[(idx >> 5) * NC + c0 + (idx & 31)];
  __syncthreads();
  const int row0 = blockIdx.x * 64 + (tid >> 5) * 8;
  const int col = tid & 31;
  float acc[8];
  gemm_core(x, 256, 256, Bs, row0, col, acc);
  if (gat) {
    #pragma unroll
    for (int r = 0; r < 8; ++r) h1[(size_t)(row0 + r) * 128 + c0 + col] = acc[r];
    const int head = c0 >> 6;
    const float asw = as_w[head * 64 + (c0 & 63) + col];
    const float adw = ad_w[head * 64 + (c0 & 63) + col];
    float ps[8], pd[8];
    #pragma unroll
    for (int r = 0; r < 8; ++r) { ps[r] = acc[r] * asw; pd[r] = acc[r] * adw; }
    #pragma unroll
    for (int m = 16; m >= 1; m >>= 1)
      #pragma unroll
      for (int r = 0; r < 8; ++r) { ps[r] += __shfl_xor(ps[r], m); pd[r] += __shfl_xor(pd[r], m); }
    if (col == 0) {
      #pragma unroll
      for (int r = 0; r < 8; ++r) {
        atomicAdd(&a_s1[(row0 + r) * 2 + head], ps[r]);
        atomicAdd(&a_d1[(row0 + r) * 2 + head], pd[r]);
      }
    }
  } else {
    #pragma unroll
    for (int r = 0; r < 8; ++r) hg1[(size_t)(row0 + r) * 64 + c0 + col] = acc[r];
  }
}

// ---------------- GAT aggregation ----------------
template<int H, int C>
__device__ __forceinline__ void gat_agg_body(const float* __restrict__ h,
    const float* __restrict__ a_s, const float* __restrict__ a_d,
    const int* __restrict__ off, const int* __restrict__ srcs,
    const float* __restrict__ bias, float* __restrict__ out, int ldout, int b) {
  constexpr int HC = H * C;
  const int tid = threadIdx.x;
  const int hd = tid / C;
  const int r0 = off[b], r1 = off[b + 1];
  __shared__ int s_src[HC];
  __shared__ float s_w[HC][H];
  float ad[H];
  #pragma unroll
  for (int hh = 0; hh < H; ++hh) ad[hh] = a_d[b * H + hh];
  float acc = 0.f, den = 0.f;
  for (int base = r0; base < r1; base += HC) {
    __syncthreads();
    int e = base + tid;
    if (e < r1) {
      int sv = srcs[e];
      s_src[tid] = sv;
      #pragma unroll
      for (int hh = 0; hh < H; ++hh) {
        float xv = a_s[sv * H + hh] + ad[hh];
        xv = xv > 0.f ? xv : 0.2f * xv;     // leaky_relu 0.2
        s_w[tid][hh] = __expf(xv);
      }
    }
    __syncthreads();
    int cnt = min(HC, r1 - base);
    for (int j = 0; j < cnt; ++j) {
      float wv = s_w[j][hd];
      den += wv;
      acc = fmaf(wv, h[(size_t)s_src[j] * HC + tid], acc);
    }
  }
  float o = acc / den + bias[tid];
  out[(size_t)b * ldout + tid] = o > 0.f ? o : (__expf(o) - 1.f);  // elu
}

template<int H, int C>
__global__ void gat_agg_k(const float* __restrict__ h, const float* __restrict__ a_s,
                          const float* __restrict__ a_d, const int* __restrict__ off,
                          const int* __restrict__ srcs, const float* __restrict__ bias,
                          float* __restrict__ out, int ldout) {
  gat_agg_body<H, C>(h, a_s, a_d, off, srcs, bias, out, ldout, blockIdx.x);
}

// ---------------- merged: gat1 aggregation (blocks 0..NN) + gcn1 agg+gemv (2 nodes/blk) ----
__global__ __launch_bounds__(128) void agg1_k(
    const float* __restrict__ h1, const float* __restrict__ a_s1, const float* __restrict__ a_d1,
    const int* __restrict__ off_t, const int* __restrict__ src_t,
    const float* __restrict__ gat1_b, float* __restrict__ g1out,
    const float* __restrict__ hg1, const int* __restrict__ off_e, const int* __restrict__ src_e,
    const float* __restrict__ gcn1_b, const float* __restrict__ gcn2_W, float* __restrict__ h2g) {
  const int tid = threadIdx.x;
  if (blockIdx.x < NN) {
    gat_agg_body<2, 64>(h1, a_s1, a_d1, off_t, src_t, gat1_b, g1out, 128, blockIdx.x);
  } else {
    const int nb = (blockIdx.x - NN) * 2;
    const int sub = tid >> 6, t = tid & 63;
    const int node = nb + sub;
    __shared__ int s_src2[2][64];
    __shared__ float s_nrm2[2][64];
    __shared__ float s_row2[2][64];
    const int r0 = off_e[node], r1 = off_e[node + 1];
    const int cA = off_e[nb + 1] - off_e[nb];
    const int cB = off_e[nb + 2] - off_e[nb + 1];
    const int trips = (max(cA, cB) + 63) >> 6;
    float dinv_b = rsqrtf((float)max(r1 - r0, 1));
    float acc = 0.f;
    for (int it = 0; it < trips; ++it) {
      __syncthreads();
      int e = r0 + it * 64 + t;
      if (e < r1) {
        int sv = src_e[e];
        s_src2[sub][t] = sv;
        int ds = off_e[sv + 1] - off_e[sv];
        s_nrm2[sub][t] = dinv_b * rsqrtf((float)max(ds, 1));
      }
      __syncthreads();
      int cnt = min(64, r1 - (r0 + it * 64));
      for (int j = 0; j < cnt; ++j)
        acc = fmaf(s_nrm2[sub][j], hg1[(size_t)s_src2[sub][j] * 64 + t], acc);
    }
    s_row2[sub][t] = fmaxf(acc + gcn1_b[t], 0.f);
    __syncthreads();
    float acc2 = 0.f;
    for (int k = 0; k < 64; ++k)
      acc2 = fmaf(s_row2[sub][k], gcn2_W[k * 64 + t], acc2);
    h2g[(size_t)node * 64 + t] = acc2;
  }
}

// ---------------- merged: mm_gat2 (blocks 0..256) + gcn_agg2 (4 nodes/blk) ----------------
__global__ __launch_bounds__(256) void mm2_k(
    const float* __restrict__ g1out, const float* __restrict__ gat2_W,
    const float* __restrict__ gat2_as, const float* __restrict__ gat2_ad,
    float* __restrict__ h2, float* __restrict__ a_s2, float* __restrict__ a_d2,
    const float* __restrict__ h2g, const int* __restrict__ off_e, const int* __restrict__ src_e,
    const float* __restrict__ gcn2_b, float* __restrict__ hekg) {
  const int tid = threadIdx.x;
  if (blockIdx.x < 256) {
    __shared__ float Bs[128 * 32];
    const int bx = blockIdx.x & 127;
    const int c0 = (blockIdx.x >> 7) * 32;
    for (int idx = tid; idx < 128 * 32; idx += 256)
      Bs[idx] = gat2_W[(idx >> 5) * 64 + c0 + (idx & 31)];
    __syncthreads();
    const int row0 = bx * 64 + (tid >> 5) * 8;
    const int col = tid & 31;
    float acc[8];
    gemm_core(g1out, 128, 128, Bs, row0, col, acc);
    const float asw = gat2_as[c0 + col];
    const float adw = gat2_ad[c0 + col];
    float ps[8], pd[8];
    #pragma unroll
    for (int r = 0; r < 8; ++r) {
      h2[(size_t)(row0 + r) * 64 + c0 + col] = acc[r];
      ps[r] = acc[r] * asw; pd[r] = acc[r] * adw;
    }
    #pragma unroll
    for (int m = 16; m >= 1; m >>= 1)
      #pragma unroll
      for (int r = 0; r < 8; ++r) { ps[r] += __shfl_xor(ps[r], m); pd[r] += __shfl_xor(pd[r], m); }
    if (col == 0) {
      #pragma unroll
      for (int r = 0; r < 8; ++r) {
        atomicAdd(&a_s2[row0 + r], ps[r]);
        atomicAdd(&a_d2[row0 + r], pd[r]);
      }
    }
  } else {
    const int nb = (blockIdx.x - 256) * 4;
    const int sub = tid >> 6, t = tid & 63;
    const int node = nb + sub;
    __shared__ int s_src4[4][64];
    __shared__ float s_nrm4[4][64];
    const int r0 = off_e[node], r1 = off_e[node + 1];
    int cmax = 0;
    #pragma unroll
    for (int i = 0; i < 4; ++i) cmax = max(cmax, off_e[nb + i + 1] - off_e[nb + i]);
    const int trips = (cmax + 63) >> 6;
    float dinv_b = rsqrtf((float)max(r1 - r0, 1));
    float acc = 0.f;
    for (int it = 0; it < trips; ++it) {
      __syncthreads();
      int e = r0 + it * 64 + t;
      if (e < r1) {
        int sv = src_e[e];
        s_src4[sub][t] = sv;
        int ds = off_e[sv + 1] - off_e[sv];
        s_nrm4[sub][t] = dinv_b * rsqrtf((float)max(ds, 1));
      }
      __syncthreads();
      int cnt = min(64, r1 - (r0 + it * 64));
      for (int j = 0; j < cnt; ++j)
        acc = fmaf(s_nrm4[sub][j], h2g[(size_t)s_src4[sub][j] * 64 + t], acc);
    }
    hekg[(size_t)node * 64 + t] = fmaxf(acc + gcn2_b[t], 0.f);
  }
}

// ---------------- qkv projections (+V transpose) ----------------
__global__ __launch_bounds__(256) void mm_qkv_k(const float* __restrict__ htkg,
    const float* __restrict__ hekg,
    const float* __restrict__ Wq, const float* __restrict__ bq,
    const float* __restrict__ Wk, const float* __restrict__ bk,
    const float* __restrict__ Wv, const float* __restrict__ bv,
    unsigned short* __restrict__ qb, unsigned short* __restrict__ kb,
    unsigned short* __restrict__ Vt) {
  __shared__ float Bs[64 * 32];
  __shared__ float Ts[32][65];
  const int tid = threadIdx.x, by = blockIdx.y;
  const int kind = by >> 1;
  const int c0 = (by & 1) * 32;
  const float* A = (kind == 0) ? htkg : hekg;
  const float* B = (kind == 0) ? Wq : (kind == 1) ? Wk : Wv;
  const float* bias = (kind == 0) ? bq : (kind == 1) ? bk : bv;
  for (int idx = tid; idx < 64 * 32; idx += 256)
    Bs[idx] = B[(idx >> 5) * 64 + c0 + (idx & 31)];
  __syncthreads();
  const int row0 = blockIdx.x * 64 + (tid >> 5) * 8;
  const int col = tid & 31;
  float acc[8];
  gemm_core(A, 64, 64, Bs, row0, col, acc);
  const float bb = bias[c0 + col];
  if (kind == 0) {
    const float SCL = 0.17677669529663687f * 1.4426950408889634f;  // 1/sqrt(32) * log2(e)
    #pragma unroll
    for (int r = 0; r < 8; ++r)
      qb[(size_t)(row0 + r) * 64 + c0 + col] = f2bf((acc[r] + bb) * SCL);
  } else if (kind == 1) {
    #pragma unroll
    for (int r = 0; r < 8; ++r)
      kb[(size_t)(row0 + r) * 64 + c0 + col] = f2bf(acc[r] + bb);
  } else {
    const int rl = (tid >> 5) * 8;
    #pragma unroll
    for (int r = 0; r < 8; ++r) Ts[col][rl + r] = acc[r] + bb;
    __syncthreads();
    const int c = tid >> 3, rr = (tid & 7) * 8;
    short8 pk;
    #pragma unroll
    for (int j = 0; j < 8; ++j) pk[j] = (short)f2bf(Ts[c][rr + j]);
    *(short8*)(Vt + (size_t)(c0 + c) * NN + blockIdx.x * 64 + rr) = pk;
  }
}

// ---------------- fused attention: l-loop, then P/attn/O loop ----------------
// grid 512 (one block per 16 q-rows); wave strip = 2048 keys.
__global__ __launch_bounds__(256) void att_fused(
    const unsigned short* __restrict__ qb, const unsigned short* __restrict__ kb,
    const unsigned short* __restrict__ Vt,
    float* __restrict__ attn, float* __restrict__ O) {
  __shared__ __align__(16) float Esh[4][2][16 * 36];  // per-wave P staging [16q x 32k, stride 36]
  __shared__ float lsh[4][16][2];
  __shared__ float Osh[16 * 64];
  const int tid = threadIdx.x;
  const int lane = tid & 63, wv = tid >> 6;
  const int ql = lane & 15, quad = lane >> 4;
  const int qt0 = blockIdx.x * 16;
  const floatx4 zf = {0.f, 0.f, 0.f, 0.f};

  for (int idx = tid; idx < 16 * 64; idx += 256) Osh[idx] = 0.f;

  short8 qf[2];
  #pragma unroll
  for (int h = 0; h < 2; ++h)
    qf[h] = *(const short8*)(qb + (size_t)(qt0 + ql) * 64 + h * 32 + quad * 8);

  // ---- loop 1: row sums ----
  float lacc[2][4];
  #pragma unroll
  for (int h = 0; h < 2; ++h)
    #pragma unroll
    for (int r = 0; r < 4; ++r) lacc[h][r] = 0.f;
  int kbase = wv * 2048;
  for (int it = 0; it < 64; ++it, kbase += 32) {
    short8 kf[2][2];
    #pragma unroll
    for (int kt = 0; kt < 2; ++kt)
      #pragma unroll
      for (int h = 0; h < 2; ++h)
        kf[kt][h] = *(const short8*)(kb + (size_t)(kbase + kt * 16 + ql) * 64 + h * 32 + quad * 8);
    #pragma unroll
    for (int h = 0; h < 2; ++h)
      #pragma unroll
      for (int kt = 0; kt < 2; ++kt) {
        floatx4 s = __builtin_amdgcn_mfma_f32_16x16x32_bf16(qf[h], kf[kt][h], zf, 0, 0, 0);
        #pragma unroll
        for (int r = 0; r < 4; ++r) lacc[h][r] += __builtin_amdgcn_exp2f(s[r]);
      }
  }
  #pragma unroll
  for (int o = 8; o >= 1; o >>= 1)
    #pragma unroll
    for (int h = 0; h < 2; ++h)
      #pragma unroll
      for (int r = 0; r < 4; ++r)
        lacc[h][r] += __shfl_xor(lacc[h][r], o, 16);
  if (ql == 0) {
    #pragma unroll
    for (int h = 0; h < 2; ++h)
      #pragma unroll
      for (int r = 0; r < 4; ++r)
        lsh[wv][quad * 4 + r][h] = lacc[h][r];
  }
  __syncthreads();
  float invl[2][4];
  #pragma unroll
  for (int h = 0; h < 2; ++h)
    #pragma unroll
    for (int r = 0; r < 4; ++r) {
      int row = quad * 4 + r;
      invl[h][r] = 1.0f / (lsh[0][row][h] + lsh[1][row][h] + lsh[2][row][h] + lsh[3][row][h]);
    }

  // ---- loop 2: P, attn writes (dwordx4 full lines), PV ----
  floatx4 oacc[2][2];
  #pragma unroll
  for (int h = 0; h < 2; ++h)
    #pragma unroll
    for (int hf = 0; hf < 2; ++hf) oacc[h][hf] = zf;

  const int r8 = lane >> 3;            // 0..7 row within half-tile
  const int c4 = (lane & 7) * 4;       // 0..28 col group
  kbase = wv * 2048;
  for (int it = 0; it < 64; ++it, kbase += 32) {
    short8 kf[2][2], vf[2][2];
    #pragma unroll
    for (int kt = 0; kt < 2; ++kt)
      #pragma unroll
      for (int h = 0; h < 2; ++h)
        kf[kt][h] = *(const short8*)(kb + (size_t)(kbase + kt * 16 + ql) * 64 + h * 32 + quad * 8);
    #pragma unroll
    for (int h = 0; h < 2; ++h)
      #pragma unroll
      for (int hf = 0; hf < 2; ++hf)
        vf[h][hf] = *(const short8*)(Vt + (size_t)(h * 32 + hf * 16 + ql) * NN + kbase + quad * 8);

    floatx4 p[2][2];  // [head][kt]
    #pragma unroll
    for (int h = 0; h < 2; ++h)
      #pragma unroll
      for (int kt = 0; kt < 2; ++kt) {
        floatx4 s = __builtin_amdgcn_mfma_f32_16x16x32_bf16(qf[h], kf[kt][h], zf, 0, 0, 0);
        #pragma unroll
        for (int r = 0; r < 4; ++r)
          p[h][kt][r] = __builtin_amdgcn_exp2f(s[r]) * invl[h][r];
      }
    // C-layout -> LDS (per-wave staging)
    #pragma unroll
    for (int h = 0; h < 2; ++h)
      #pragma unroll
      for (int kt = 0; kt < 2; ++kt)
        #pragma unroll
        for (int r = 0; r < 4; ++r)
          Esh[wv][h][(quad * 4 + r) * 36 + kt * 16 + ql] = p[h][kt][r];
    // attn head-mean: row-major readback, full-cache-line dwordx4 stores
    {
      const float4 a0 = *(const float4*)&Esh[wv][0][r8 * 36 + c4];
      const float4 b0 = *(const float4*)&Esh[wv][1][r8 * 36 + c4];
      const float4 a1 = *(const float4*)&Esh[wv][0][(r8 + 8) * 36 + c4];
      const float4 b1 = *(const float4*)&Esh[wv][1][(r8 + 8) * 36 + c4];
      float4 m0, m1;
      m0.x = 0.5f * (a0.x + b0.x); m0.y = 0.5f * (a0.y + b0.y);
      m0.z = 0.5f * (a0.z + b0.z); m0.w = 0.5f * (a0.w + b0.w);
      m1.x = 0.5f * (a1.x + b1.x); m1.y = 0.5f * (a1.y + b1.y);
      m1.z = 0.5f * (a1.z + b1.z); m1.w = 0.5f * (a1.w + b1.w);
      *(float4*)&attn[(size_t)(qt0 + r8) * NN + kbase + c4] = m0;
      *(float4*)&attn[(size_t)(qt0 + r8 + 8) * NN + kbase + c4] = m1;
    }
    // LDS -> A-layout, PV mfma
    #pragma unroll
    for (int h = 0; h < 2; ++h) {
      const float* ep = &Esh[wv][h][ql * 36 + quad * 8];
      float4 x0 = *(const float4*)ep;
      float4 x1 = *(const float4*)(ep + 4);
      short8 ef;
      ef[0] = (short)f2bf(x0.x); ef[1] = (short)f2bf(x0.y);
      ef[2] = (short)f2bf(x0.z); ef[3] = (short)f2bf(x0.w);
      ef[4] = (short)f2bf(x1.x); ef[5] = (short)f2bf(x1.y);
      ef[6] = (short)f2bf(x1.z); ef[7] = (short)f2bf(x1.w);
      #pragma unroll
      for (int hf = 0; hf < 2; ++hf)
        oacc[h][hf] = __builtin_amdgcn_mfma_f32_16x16x32_bf16(ef, vf[h][hf], oacc[h][hf], 0, 0, 0);
    }
  }
  #pragma unroll
  for (int h = 0; h < 2; ++h)
    #pragma unroll
    for (int hf = 0; hf < 2; ++hf)
      #pragma unroll
      for (int r = 0; r < 4; ++r)
        atomicAdd(&Osh[(quad * 4 + r) * 64 + h * 32 + hf * 16 + ql], oacc[h][hf][r]);
  __syncthreads();
  for (int idx = tid; idx < 16 * 64; idx += 256)
    O[(size_t)qt0 * 64 + idx] = Osh[idx];
}

// ---------------- tail: h_attn=O@Wo+bo ; y1=relu([htkg|h_attn]@fc1+b) ; pred=y1@fc2+b ----
__global__ __launch_bounds__(256) void tail_k(const float* __restrict__ O,
    const float* __restrict__ htkg, const float* __restrict__ Wo, const float* __restrict__ bo,
    const float* __restrict__ fc1W, const float* __restrict__ fc1b,
    const float* __restrict__ fc2W, const float* __restrict__ fc2b,
    float* __restrict__ pred) {
  __shared__ float Ws[8192];
  __shared__ float T1[2048];
  __shared__ float T2[2048];
  const int tid = threadIdx.x;
  const int col = tid & 63, rg = tid >> 6;
  const int rowbase = blockIdx.x * 32;
  for (int i = tid; i < 2048; i += 256) T1[i] = O[(size_t)rowbase * 64 + i];
  for (int i = tid; i < 4096; i += 256) Ws[i] = Wo[i];
  const float rbo = bo[col], rf1b = fc1b[col], rf2 = fc2W[col], rf2b = fc2b[0];
  __syncthreads();
  float ha[8];
  #pragma unroll
  for (int r = 0; r < 8; ++r) {
    const int row = rg * 8 + r;
    float acc = rbo;
    for (int k = 0; k < 64; ++k) acc = fmaf(T1[row * 64 + k], Ws[k * 64 + col], acc);
    ha[r] = acc;
  }
  __syncthreads();
  #pragma unroll
  for (int r = 0; r < 8; ++r) T2[(rg * 8 + r) * 64 + col] = ha[r];
  for (int i = tid; i < 2048; i += 256) T1[i] = htkg[(size_t)rowbase * 64 + i];
  for (int i = tid; i < 8192; i += 256) Ws[i] = fc1W[i];
  __syncthreads();
  #pragma unroll
  for (int r = 0; r < 8; ++r) {
    const int row = rg * 8 + r;
    float acc = rf1b;
    for (int k = 0; k < 64; ++k) acc = fmaf(T1[row * 64 + k], Ws[k * 64 + col], acc);
    for (int k = 0; k < 64; ++k) acc = fmaf(T2[row * 64 + k], Ws[(64 + k) * 64 + col], acc);
    float y = fmaxf(acc, 0.f);
    float v = y * rf2;
    #pragma unroll
    for (int m = 32; m >= 1; m >>= 1) v += __shfl_xor(v, m);
    if (col == 0) pred[rowbase + row] = v + rf2b;
  }
}

extern "C" void kernel_launch(void* const* d_in, const int* in_sizes, int n_in,
                              void* d_out, int out_size, void* d_ws, size_t ws_size,
                              hipStream_t stream) {
  (void)in_sizes; (void)n_in; (void)out_size; (void)ws_size;
  const float* x       = (const float*)d_in[0];
  const int*   ei_t    = (const int*)d_in[1];
  const int*   ei_e    = (const int*)d_in[2];
  const float* gat1_W  = (const float*)d_in[3];
  const float* gat1_as = (const float*)d_in[4];
  const float* gat1_ad = (const float*)d_in[5];
  const float* gat1_b  = (const float*)d_in[6];
  const float* gat2_W  = (const float*)d_in[7];
  const float* gat2_as = (const float*)d_in[8];
  const float* gat2_ad = (const float*)d_in[9];
  const float* gat2_b  = (const float*)d_in[10];
  const float* gcn1_W  = (const float*)d_in[11];
  const float* gcn1_b  = (const float*)d_in[12];
  const float* gcn2_W  = (const float*)d_in[13];
  const float* gcn2_b  = (const float*)d_in[14];
  const float* Wq = (const float*)d_in[15]; const float* bq = (const float*)d_in[16];
  const float* Wk = (const float*)d_in[17]; const float* bk = (const float*)d_in[18];
  const float* Wv = (const float*)d_in[19]; const float* bv = (const float*)d_in[20];
  const float* Wo = (const float*)d_in[21]; const float* bo = (const float*)d_in[22];
  const float* fc1_W = (const float*)d_in[23]; const float* fc1_b = (const float*)d_in[24];
  const float* fc2_W = (const float*)d_in[25]; const float* fc2_b = (const float*)d_in[26];

  float* out  = (float*)d_out;
  float* attn = out + NN;   // [N, N] fp32, after pred[N]

  char* wsp = (char*)d_ws;
  size_t ofs = 0;
  auto take = [&](size_t bytes) -> char* {
    char* p = wsp + ofs;
    ofs = (ofs + bytes + 255) & ~(size_t)255;
    return p;
  };
  // ---- contiguous zero-init region first (single memset) ----
  int*   pos_t = (int*)take(NN * 4);
  int*   pos_e = (int*)take(NN * 4);
  float* a_s1  = (float*)take((size_t)NN * 2 * 4);
  float* a_d1  = (float*)take((size_t)NN * 2 * 4);
  float* a_s2  = (float*)take((size_t)NN * 4);
  float* a_d2  = (float*)take((size_t)NN * 4);
  const size_t zero_span = ofs;
  // ---- rest ----
  int* off_t = (int*)take((NN + 1) * 4);
  int* off_e = (int*)take((NN + 1) * 4);
  int* src_t = (int*)take((size_t)ET * 4);
  int* src_e = (int*)take((size_t)ET * 4);
  float* h1    = (float*)take((size_t)NN * 128 * 4);
  float* g1out = (float*)take((size_t)NN * 128 * 4);
  float* h2    = (float*)take((size_t)NN * 64 * 4);
  float* htkg  = (float*)take((size_t)NN * 64 * 4);
  float* hg1   = (float*)take((size_t)NN * 64 * 4);
  float* h2g   = (float*)take((size_t)NN * 64 * 4);
  float* hekg  = (float*)take((size_t)NN * 64 * 4);
  unsigned short* qb = (unsigned short*)take((size_t)NN * 64 * 2);
  unsigned short* kb = (unsigned short*)take((size_t)NN * 64 * 2);
  unsigned short* Vt = (unsigned short*)take((size_t)64 * NN * 2);
  float* Obuf  = (float*)take((size_t)NN * 64 * 4);

  hipMemsetAsync(wsp, 0, zero_span, stream);

  // CSR for both graphs
  edge_hist2_k<<<2 * ET / 256, 256, 0, stream>>>(ei_t, ei_e, pos_t, pos_e);
  scan2_k<<<2, 1024, 0, stream>>>(pos_t, off_t, pos_e, off_e);
  edge_scatter2_k<<<2 * ET / 256, 256, 0, stream>>>(ei_t, ei_e, pos_t, pos_e, src_t, src_e);

  // x projections for both branches + gat1 att_sd epilogue
  mm_x_k<<<dim3(128, 6), 256, 0, stream>>>(x, gat1_W, gcn1_W, gat1_as, gat1_ad,
                                           h1, hg1, a_s1, a_d1);
  // merged gat1-agg + gcn1-agg+gemv
  agg1_k<<<NN + NN / 2, 128, 0, stream>>>(h1, a_s1, a_d1, off_t, src_t, gat1_b, g1out,
                                          hg1, off_e, src_e, gcn1_b, gcn2_W, h2g);
  // merged mm_gat2 + gcn_agg2
  mm2_k<<<256 + NN / 4, 256, 0, stream>>>(g1out, gat2_W, gat2_as, gat2_ad, h2, a_s2, a_d2,
                                          h2g, off_e, src_e, gcn2_b, hekg);
  // gat layer-2 aggregation
  gat_agg_k<1, 64><<<NN, 64, 0, stream>>>(h2, a_s2, a_d2, off_t, src_t, gat2_b, htkg, 64);

  // qkv projections + V transpose
  mm_qkv_k<<<dim3(128, 6), 256, 0, stream>>>(htkg, hekg, Wq, bq, Wk, bk, Wv, bv, qb, kb, Vt);

  // fused attention (single kernel: l-loop then P/attn/O loop)
  att_fused<<<512, 256, 0, stream>>>(qb, kb, Vt, attn, Obuf);

  // fused epilogue: Wo + fc1 + fc2
  tail_k<<<256, 256, 0, stream>>>(Obuf, htkg, Wo, bo, fc1_W, fc1_b, fc2_W, fc2_b, out);
}